// Round 6
// baseline (1191.828 us; speedup 1.0000x reference)
//
#include <hip/hip_runtime.h>
#include <math.h>

typedef unsigned long long ull;

#define NN1 50000
#define EE  600000
#define KK1 25000
#define KK2 12500

#define NB (1<<18)      // rank buckets
#define BSHIFT 46       // 64-18

#define CDIV(a,b) (((a)+(b)-1)/(b))

__device__ __forceinline__ ull encd(double d){
  ull u = (ull)__double_as_longlong(d);
  return (u & 0x8000000000000000ULL) ? ~u : (u | 0x8000000000000000ULL);
}
__device__ __forceinline__ double decd(ull u){
  ull v = (u & 0x8000000000000000ULL) ? (u & 0x7FFFFFFFFFFFFFFFULL) : ~u;
  return __longlong_as_double((long long)v);
}
__device__ __forceinline__ double lrelu(double z){ return z > 0.0 ? z : 0.2*z; }

__global__ void zeroi_k(int* __restrict__ p, int n){
  int t = blockIdx.x*blockDim.x + threadIdx.x;
  if (t < n) p[t] = 0;
}
__global__ void zero2_k(int* __restrict__ a, int* __restrict__ b, int n){
  int t = blockIdx.x*blockDim.x + threadIdx.x;
  if (t < n){ a[t] = 0; b[t] = 0; }
}

// ---------------- GEMM: Out[n,256] = A[n,256] @ W[256,256], f64 math ----------------
// 128x64 tile, BK=32, 8x4 f64 acc/thread. LDS rows 16B-aligned (132 / 68 pads).
// k ascends globally -> accumulation order identical to prior rounds (bit-exact).
template<typename TA, typename TS>
__global__ __launch_bounds__(256) void gemm_k(const TA* __restrict__ A, const float* __restrict__ W,
                                              double* __restrict__ Out, int n){
  __shared__ TS    As[32][132];   // 132*4=528=33*16 ; 132*8=1056=66*16 -> b128-aligned rows
  __shared__ float Bs[32][68];    // 68*4=272=17*16
  const int tid = threadIdx.x;
  const int r0 = blockIdx.x*128, c0 = blockIdx.y*64;
  const int ty = tid>>4, tx = tid&15;          // ty:16 row-groups of 8, tx:16 col-groups of 4
  double acc[8][4] = {};
  for (int k0 = 0; k0 < 256; k0 += 32){
    int kA = tid & 31, rA = tid >> 5;          // coalesced A reads (32 consecutive k per row)
    #pragma unroll
    for (int i=0;i<16;i++){
      int rr = rA + i*8;
      int gr = r0 + rr;
      As[kA][rr] = (gr < n) ? (TS)A[(long)gr*256 + k0 + kA] : (TS)0;
    }
    int cB = tid & 63, kB = tid >> 6;          // coalesced W reads
    #pragma unroll
    for (int i=0;i<8;i++){
      int kk = kB + i*4;
      Bs[kk][cB] = W[(k0+kk)*256 + c0 + cB];
    }
    __syncthreads();
    #pragma unroll 4
    for (int k=0;k<32;k++){
      double a[8], b[4];
      #pragma unroll
      for (int i=0;i<8;i++) a[i] = (double)As[k][ty*8+i];   // broadcast reads
      #pragma unroll
      for (int j=0;j<4;j++) b[j] = (double)Bs[k][tx*4+j];   // <=4-way
      #pragma unroll
      for (int i=0;i<8;i++)
        #pragma unroll
        for (int j=0;j<4;j++)
          acc[i][j] = fma(a[i], b[j], acc[i][j]);
    }
    __syncthreads();
  }
  #pragma unroll
  for (int i=0;i<8;i++){
    int gr = r0 + ty*8 + i;
    if (gr < n){
      #pragma unroll
      for (int j=0;j<4;j++)
        Out[(long)gr*256 + c0 + tx*4 + j] = acc[i][j];
    }
  }
}

// ---------------- attention coefficients + score projection hp = h . p ----------------
__global__ void attn_k(const double* __restrict__ Hh, const float* __restrict__ asrc,
                       const float* __restrict__ adst, const float* __restrict__ p,
                       double* __restrict__ als, double* __restrict__ ald,
                       double* __restrict__ hp){
  int i = blockIdx.x; int ch = threadIdx.x; int head = ch>>6; int lane = ch&63;
  double hv = Hh[(long)i*256 + ch];
  double vs = hv * (double)asrc[ch];
  double vd = hv * (double)adst[ch];
  double vp = hv * (double)p[ch];
  for (int off=32; off; off>>=1){
    vs += __shfl_down(vs, off); vd += __shfl_down(vd, off); vp += __shfl_down(vp, off);
  }
  if (lane == 0){ als[i*4+head] = vs; ald[i*4+head] = vd; hp[i*4+head] = vp; }
}

// init segment-max with self-loop value; zero degree array in same pass
__global__ void initm_k(const double* __restrict__ als, const double* __restrict__ ald,
                        ull* __restrict__ menc, int* __restrict__ deg, int n){
  int t = blockIdx.x*blockDim.x + threadIdx.x;
  if (t >= 4*n) return;
  menc[t] = encd(lrelu(als[t] + ald[t]));
  if (t < n) deg[t] = 0;
}

// edge max + degree count in one pass
__global__ void edgemax_k(const int* __restrict__ src, const int* __restrict__ dst,
                          const int* __restrict__ msk, const double* __restrict__ als,
                          const double* __restrict__ ald, ull* __restrict__ menc,
                          int* __restrict__ deg, int e){
  int t = blockIdx.x*blockDim.x + threadIdx.x;
  if (t >= e) return;
  if (msk && !msk[t]) return;
  int s = src[t], d = dst[t];
  atomicAdd(&deg[d], 1);
  #pragma unroll
  for (int h=0;h<4;h++){
    double ev = lrelu(als[s*4+h] + ald[d*4+h]);
    atomicMax(&menc[d*4+h], encd(ev));
  }
}

__global__ void wself_k(const double* __restrict__ als, const double* __restrict__ ald,
                        const ull* __restrict__ menc, double* __restrict__ wself, int total){
  int t = blockIdx.x*blockDim.x + threadIdx.x;
  if (t >= total) return;
  double e = lrelu(als[t] + ald[t]);
  wself[t] = exp(e - decd(menc[t]));
}

__global__ void edgew_k(const int* __restrict__ src, const int* __restrict__ dst,
                        const int* __restrict__ msk, const double* __restrict__ als,
                        const double* __restrict__ ald, const ull* __restrict__ menc,
                        double* __restrict__ wedge, int e){
  int t = blockIdx.x*blockDim.x + threadIdx.x;
  if (t >= e) return;
  int s = src[t], d = dst[t];
  bool ok = (!msk) || (msk[t] != 0);
  #pragma unroll
  for (int h=0;h<4;h++){
    double w = 0.0;
    if (ok){
      double ev = lrelu(als[s*4+h] + ald[d*4+h]);
      w = exp(ev - decd(menc[d*4+h]));
    }
    wedge[(long)t*4+h] = w;
  }
}

// ---------------- hierarchical scan (blocks of 256) ----------------
__global__ __launch_bounds__(256) void scanA_k(int* __restrict__ a, int* __restrict__ btot, int n){
  __shared__ int s[256];
  int g = blockIdx.x*256 + threadIdx.x;
  s[threadIdx.x] = (g < n) ? a[g] : 0;
  __syncthreads();
  for (int off=1; off<256; off<<=1){
    int t = (threadIdx.x >= off) ? s[threadIdx.x-off] : 0;
    __syncthreads();
    s[threadIdx.x] += t;
    __syncthreads();
  }
  if (g < n) a[g] = s[threadIdx.x];
  if (threadIdx.x == 255) btot[blockIdx.x] = s[255];
}

__global__ __launch_bounds__(1024) void scanB_k(int* __restrict__ btot, int nb){
  __shared__ int s[1024];
  int t = threadIdx.x;
  s[t] = (t < nb) ? btot[t] : 0;
  __syncthreads();
  for (int off=1; off<1024; off<<=1){
    int v = (t >= off) ? s[t-off] : 0;
    __syncthreads();
    s[t] += v;
    __syncthreads();
  }
  if (t < nb) btot[t] = s[t];
}

__global__ void scanC_rowptr_k(const int* __restrict__ a, const int* __restrict__ btot,
                               int* __restrict__ rowptr, int* __restrict__ cursor, int n){
  int g = blockIdx.x*blockDim.x + threadIdx.x;
  if (g >= n) return;
  int B = g >> 8;
  int off = (B > 0) ? btot[B-1] : 0;
  rowptr[g+1] = a[g] + off;
  cursor[g] = 0;
  if (g == 0) rowptr[0] = 0;
}

__global__ void scanC_above_k(const int* __restrict__ a, const int* __restrict__ btot,
                              int* __restrict__ habove, int nelems, int nbins){
  int g = blockIdx.x*blockDim.x + threadIdx.x;
  if (g >= nbins) return;
  int B = g >> 8;
  int off = (B > 0) ? btot[B-1] : 0;
  habove[g] = nelems - (a[g] + off);
}

__global__ void place_k(const int* __restrict__ dst, const int* __restrict__ msk,
                        const int* __restrict__ rowptr, int* __restrict__ cursor,
                        int* __restrict__ csr, int e){
  int t = blockIdx.x*blockDim.x + threadIdx.x;
  if (t >= e) return;
  if (msk && !msk[t]) return;
  int d = dst[t];
  int slot = atomicAdd(&cursor[d], 1);
  csr[rowptr[d] + slot] = t;
}

// ---------------- score via precomputed hp ----------------
__global__ void score_csr_k(const double* __restrict__ hp, const double* __restrict__ wed,
                            const double* __restrict__ wse, const int* __restrict__ srcA,
                            const int* __restrict__ rowptr, const int* __restrict__ csr,
                            const double* __restrict__ nrmbp, double* __restrict__ z, int n){
  int g = blockIdx.x*blockDim.x + threadIdx.x;
  int i = g>>2, h = g&3;
  if (i >= n) return;
  double ws = wse[i*4+h];
  double acc = ws * hp[(long)i*4+h];
  double den = ws;
  int b = rowptr[i], e = rowptr[i+1];
  for (int t=b; t<e; t++){
    int eid = csr[t]; int s = srcA[eid];
    double w = wed[(long)eid*4+h];
    acc = fma(w, hp[(long)s*4+h], acc);
    den += w;
  }
  double part = acc/den;
  part += __shfl_xor(part, 1);
  part += __shfl_xor(part, 2);
  if (h == 0) z[i] = (part + nrmbp[1]) / nrmbp[0];
}

// full row of X for node i (one channel per thread); deterministic denominator
__device__ __forceinline__ double gat_row(const double* __restrict__ Hh, const int* __restrict__ srcA,
                                          const int* __restrict__ rowptr, const int* __restrict__ csr,
                                          const double* __restrict__ wed, const double* __restrict__ wse,
                                          const float* __restrict__ bias, int i, int ch, int h){
  double acc = wse[i*4+h] * Hh[(long)i*256 + ch];
  double dsum = wse[i*4+h];
  int b = rowptr[i], e = rowptr[i+1];
  for (int t=b; t<e; t++){
    int eid = csr[t]; int s = srcA[eid];
    double w = wed[(long)eid*4+h];
    acc  = fma(w, Hh[(long)s*256 + ch], acc);
    dsum += w;
  }
  return acc/dsum + (double)bias[ch];
}

__global__ void aggr_gate_k(const double* __restrict__ Hh, const int* __restrict__ srcA,
                            const int* __restrict__ rowptr, const int* __restrict__ csr,
                            const double* __restrict__ wed, const double* __restrict__ wse,
                            const float* __restrict__ bias, const int* __restrict__ perm,
                            const double* __restrict__ scs, double* __restrict__ Xi){
  int r = blockIdx.x, ch = threadIdx.x, h = ch>>6;
  int i = perm[r];
  double row = gat_row(Hh, srcA, rowptr, csr, wed, wse, bias, i, ch, h);
  double v = row * scs[r];
  Xi[(long)r*256 + ch] = v > 0.0 ? v : 0.0;
}

__global__ void aggr_final_k(const double* __restrict__ Hh, const int* __restrict__ srcA,
                             const int* __restrict__ rowptr, const int* __restrict__ csr,
                             const double* __restrict__ wed, const double* __restrict__ wse,
                             const float* __restrict__ bias, const int* __restrict__ perm,
                             const double* __restrict__ scs, float* __restrict__ out){
  int r = blockIdx.x, ch = threadIdx.x, h = ch>>6;
  int i = perm[r];
  double row = gat_row(Hh, srcA, rowptr, csr, wed, wse, bias, i, ch, h);
  double v = row * scs[r];
  out[(long)r*256 + ch] = (float)(v > 0.0 ? v : 0.0);
}

// ||p|| and b.p
__global__ void pnorm_k(const float* __restrict__ p, const float* __restrict__ bias,
                        double* __restrict__ nrmbp){
  __shared__ double ws_[8];
  int tid = threadIdx.x;
  double pv = (double)p[tid];
  double v = pv*pv;
  double w = (double)bias[tid]*pv;
  for (int off=32; off; off>>=1){ v += __shfl_down(v, off); w += __shfl_down(w, off); }
  if ((tid&63)==0){ ws_[tid>>6] = v; ws_[4+(tid>>6)] = w; }
  __syncthreads();
  if (tid == 0){
    nrmbp[0] = sqrt(ws_[0]+ws_[1]+ws_[2]+ws_[3]);
    nrmbp[1] = ws_[4]+ws_[5]+ws_[6]+ws_[7];
  }
}

// ---------------- bucket-based exact ranking ----------------
__global__ void keyhist_k(const double* __restrict__ z, ull* __restrict__ k64,
                          int* __restrict__ hist, int n){
  int i = blockIdx.x*blockDim.x + threadIdx.x;
  if (i >= n) return;
  ull e = encd(z[i]);
  k64[i] = e;
  atomicAdd(&hist[(int)(e >> BSHIFT)], 1);
}

__global__ void bplace_k(const ull* __restrict__ k64, const int* __restrict__ habove,
                         int* __restrict__ cur, int* __restrict__ isort, int n){
  int i = blockIdx.x*blockDim.x + threadIdx.x;
  if (i >= n) return;
  int b = (int)(k64[i] >> BSHIFT);
  int slot = atomicAdd(&cur[b], 1);
  isort[habove[b] + slot] = i;
}

__global__ void brank_k(const ull* __restrict__ k64, const int* __restrict__ habove,
                        const int* __restrict__ isort, int* __restrict__ rank, int n){
  int i = blockIdx.x*blockDim.x + threadIdx.x;
  if (i >= n) return;
  ull ki = k64[i];
  int b = (int)(ki >> BSHIFT);
  int lo = habove[b];
  int hi = (b > 0) ? habove[b-1] : n;
  int cnt = 0;
  for (int t = lo; t < hi; t++){
    int j = isort[t];
    ull kj = k64[j];
    cnt += ((kj > ki) || (kj == ki && j < i)) ? 1 : 0;
  }
  rank[i] = lo + cnt;
}

__global__ void scatter_k(const double* __restrict__ z, const int* __restrict__ rank,
                          int* __restrict__ perm, int* __restrict__ inv,
                          double* __restrict__ scs, int n, int k){
  int i = blockIdx.x*blockDim.x + threadIdx.x;
  if (i >= n) return;
  int r = rank[i];
  inv[i] = (r < k) ? r : -1;
  if (r < k){ perm[r] = i; scs[r] = tanh(z[i]); }
}

__global__ void reindex_k(const int* __restrict__ src, const int* __restrict__ dst,
                          const int* __restrict__ inv,
                          int* __restrict__ ns, int* __restrict__ nd, int* __restrict__ nmsk, int e){
  int t = blockIdx.x*blockDim.x + threadIdx.x;
  if (t >= e) return;
  int a = inv[src[t]], b = inv[dst[t]];
  int ok = (a >= 0) && (b >= 0);
  ns[t] = ok ? a : 0; nd[t] = ok ? b : 0; nmsk[t] = ok;
}

__global__ void finedge_k(const int* __restrict__ ns, const int* __restrict__ nd,
                          const int* __restrict__ msk, const int* __restrict__ inv,
                          float* __restrict__ osrc, float* __restrict__ odst,
                          float* __restrict__ omsk, int e){
  int t = blockIdx.x*blockDim.x + threadIdx.x;
  if (t >= e) return;
  int a = inv[ns[t]], b = inv[nd[t]];
  int ok = msk[t] && (a >= 0) && (b >= 0);
  osrc[t] = (float)(ok ? a : 0);
  odst[t] = (float)(ok ? b : 0);
  omsk[t] = ok ? 1.0f : 0.0f;
}

__global__ void zerof_k(float* __restrict__ o, int n){
  int t = blockIdx.x*blockDim.x + threadIdx.x;
  if (t < n) o[t] = 0.0f;
}

extern "C" void kernel_launch(void* const* d_in, const int* in_sizes, int n_in,
                              void* d_out, int out_size, void* d_ws, size_t ws_size,
                              hipStream_t stream){
  (void)in_sizes; (void)n_in; (void)out_size; (void)ws_size;
  const float* x   = (const float*)d_in[0];
  const int*   ei  = (const int*)d_in[1];
  const float* W1  = (const float*)d_in[3];
  const float* as1 = (const float*)d_in[4];
  const float* ad1 = (const float*)d_in[5];
  const float* b1  = (const float*)d_in[6];
  const float* p1  = (const float*)d_in[7];
  const float* W2  = (const float*)d_in[8];
  const float* as2 = (const float*)d_in[9];
  const float* ad2 = (const float*)d_in[10];
  const float* b2  = (const float*)d_in[11];
  const float* p2  = (const float*)d_in[12];
  const int* src0 = ei;
  const int* dst0 = ei + EE;

  char* cur_ = (char*)d_ws;
  auto take = [&](size_t bytes)->void*{ void* p = (void*)cur_; cur_ += (bytes + 255) & ~(size_t)255; return p; };
  double* bufA = (double*)take((size_t)NN1*256*8);   // Hh1; later Hh2
  double* Xi   = (double*)take((size_t)KK1*256*8);
  double* als  = (double*)take((size_t)NN1*4*8);     // aliased by hist during pooling
  double* ald  = (double*)take((size_t)NN1*4*8);     // aliased by habove
  ull*    menc = (ull*)   take((size_t)NN1*4*8);     // aliased by bcur
  double* wse  = (double*)take((size_t)NN1*4*8);
  double* hp   = (double*)take((size_t)NN1*4*8);
  double* wed  = (double*)take((size_t)EE*4*8);
  double* sco  = (double*)take((size_t)NN1*8);
  double* scs  = (double*)take((size_t)KK1*8);
  double* nrm  = (double*)take(256);
  ull*    k64  = (ull*)   take((size_t)NN1*8);
  int* isort= (int*)take((size_t)NN1*4);
  int* rnk  = (int*)take((size_t)NN1*4);
  int* prm  = (int*)take((size_t)KK1*4);
  int* inv  = (int*)take((size_t)NN1*4);
  int* deg  = (int*)take((size_t)(NN1+1)*4);
  int* rwp  = (int*)take((size_t)(NN1+1)*4);
  int* cursr= (int*)take((size_t)NN1*4);
  int* csr  = (int*)take((size_t)EE*4);
  int* ns   = (int*)take((size_t)EE*4);
  int* nd   = (int*)take((size_t)EE*4);
  int* mk2  = (int*)take((size_t)EE*4);
  int* btot = (int*)take((size_t)1024*4);

  // bucket-rank arrays alias als/ald/menc (dead once wed/wse are built)
  int* hist   = (int*)als;
  int* habove = (int*)ald;
  int* bcur   = (int*)menc;

  double* Hh1 = bufA;
  double* Hh2 = bufA;

  float* out = (float*)d_out;
  float* o_x = out;
  float* o_s = out + (size_t)KK2*256;
  float* o_d = o_s + EE;
  float* o_m = o_d + EE;
  float* o_b = o_m + EE;

  // ---------------- stage 1: GATConv on (N1, E) ----------------
  gemm_k<float,float><<<dim3(CDIV(NN1,128),4),256,0,stream>>>(x, W1, Hh1, NN1);
  attn_k<<<NN1,256,0,stream>>>(Hh1, as1, ad1, p1, als, ald, hp);
  initm_k<<<CDIV(NN1*4,256),256,0,stream>>>(als, ald, menc, deg, NN1);
  edgemax_k<<<CDIV(EE,256),256,0,stream>>>(src0, dst0, nullptr, als, ald, menc, deg, EE);
  wself_k<<<CDIV(NN1*4,256),256,0,stream>>>(als, ald, menc, wse, NN1*4);
  edgew_k<<<CDIV(EE,256),256,0,stream>>>(src0, dst0, nullptr, als, ald, menc, wed, EE);
  scanA_k<<<CDIV(NN1,256),256,0,stream>>>(deg, btot, NN1);
  scanB_k<<<1,1024,0,stream>>>(btot, CDIV(NN1,256));
  scanC_rowptr_k<<<CDIV(NN1,256),256,0,stream>>>(deg, btot, rwp, cursr, NN1);
  place_k<<<CDIV(EE,256),256,0,stream>>>(dst0, nullptr, rwp, cursr, csr, EE);

  // ---------------- pool 1 ----------------
  pnorm_k<<<1,256,0,stream>>>(p1, b1, nrm);
  score_csr_k<<<CDIV(NN1*4,256),256,0,stream>>>(hp, wed, wse, src0, rwp, csr, nrm, sco, NN1);
  zero2_k<<<NB/256,256,0,stream>>>(hist, bcur, NB);
  keyhist_k<<<CDIV(NN1,256),256,0,stream>>>(sco, k64, hist, NN1);
  scanA_k<<<NB/256,256,0,stream>>>(hist, btot, NB);
  scanB_k<<<1,1024,0,stream>>>(btot, NB/256);
  scanC_above_k<<<NB/256,256,0,stream>>>(hist, btot, habove, NN1, NB);
  bplace_k<<<CDIV(NN1,256),256,0,stream>>>(k64, habove, bcur, isort, NN1);
  brank_k<<<CDIV(NN1,256),256,0,stream>>>(k64, habove, isort, rnk, NN1);
  scatter_k<<<CDIV(NN1,256),256,0,stream>>>(sco, rnk, prm, inv, scs, NN1, KK1);
  aggr_gate_k<<<KK1,256,0,stream>>>(Hh1, src0, rwp, csr, wed, wse, b1, prm, scs, Xi);
  reindex_k<<<CDIV(EE,256),256,0,stream>>>(src0, dst0, inv, ns, nd, mk2, EE);

  // ---------------- stage 2: GATConv on (K1, masked E) ----------------
  gemm_k<double,double><<<dim3(CDIV(KK1,128),4),256,0,stream>>>(Xi, W2, Hh2, KK1);
  attn_k<<<KK1,256,0,stream>>>(Hh2, as2, ad2, p2, als, ald, hp);
  initm_k<<<CDIV(KK1*4,256),256,0,stream>>>(als, ald, menc, deg, KK1);
  edgemax_k<<<CDIV(EE,256),256,0,stream>>>(ns, nd, mk2, als, ald, menc, deg, EE);
  wself_k<<<CDIV(KK1*4,256),256,0,stream>>>(als, ald, menc, wse, KK1*4);
  edgew_k<<<CDIV(EE,256),256,0,stream>>>(ns, nd, mk2, als, ald, menc, wed, EE);
  scanA_k<<<CDIV(KK1,256),256,0,stream>>>(deg, btot, KK1);
  scanB_k<<<1,1024,0,stream>>>(btot, CDIV(KK1,256));
  scanC_rowptr_k<<<CDIV(KK1,256),256,0,stream>>>(deg, btot, rwp, cursr, KK1);
  place_k<<<CDIV(EE,256),256,0,stream>>>(nd, mk2, rwp, cursr, csr, EE);

  // ---------------- pool 2 + outputs ----------------
  pnorm_k<<<1,256,0,stream>>>(p2, b2, nrm);
  score_csr_k<<<CDIV(KK1*4,256),256,0,stream>>>(hp, wed, wse, ns, rwp, csr, nrm, sco, KK1);
  zero2_k<<<NB/256,256,0,stream>>>(hist, bcur, NB);
  keyhist_k<<<CDIV(KK1,256),256,0,stream>>>(sco, k64, hist, KK1);
  scanA_k<<<NB/256,256,0,stream>>>(hist, btot, NB);
  scanB_k<<<1,1024,0,stream>>>(btot, NB/256);
  scanC_above_k<<<NB/256,256,0,stream>>>(hist, btot, habove, KK1, NB);
  bplace_k<<<CDIV(KK1,256),256,0,stream>>>(k64, habove, bcur, isort, KK1);
  brank_k<<<CDIV(KK1,256),256,0,stream>>>(k64, habove, isort, rnk, KK1);
  scatter_k<<<CDIV(KK1,256),256,0,stream>>>(sco, rnk, prm, inv, scs, KK1, KK2);
  aggr_final_k<<<KK2,256,0,stream>>>(Hh2, ns, rwp, csr, wed, wse, b2, prm, scs, o_x);
  finedge_k<<<CDIV(EE,256),256,0,stream>>>(ns, nd, mk2, inv, o_s, o_d, o_m, EE);
  zerof_k<<<CDIV(KK2,256),256,0,stream>>>(o_b, KK2);
}

// Round 7
// 1077.334 us; speedup vs baseline: 1.1063x; 1.1063x over previous
//
#include <hip/hip_runtime.h>
#include <math.h>

typedef unsigned long long ull;

#define NN1 50000
#define EE  600000
#define KK1 25000
#define KK2 12500

#define NB (1<<18)      // rank buckets
#define BSHIFT 46       // 64-18

#define CDIV(a,b) (((a)+(b)-1)/(b))

__device__ __forceinline__ ull encd(double d){
  ull u = (ull)__double_as_longlong(d);
  return (u & 0x8000000000000000ULL) ? ~u : (u | 0x8000000000000000ULL);
}
__device__ __forceinline__ double decd(ull u){
  ull v = (u & 0x8000000000000000ULL) ? (u & 0x7FFFFFFFFFFFFFFFULL) : ~u;
  return __longlong_as_double((long long)v);
}
__device__ __forceinline__ double lrelu(double z){ return z > 0.0 ? z : 0.2*z; }

__global__ void zero2_k(int* __restrict__ a, int* __restrict__ b, int n){
  int t = blockIdx.x*blockDim.x + threadIdx.x;
  if (t < n){ a[t] = 0; b[t] = 0; }
}

// ---------------- GEMM: Out[n,256] = A[n,256] @ W[256,256], f64 math ----------------
// 64x64 tile, BK=32, 4x4 acc (round-5 occupancy) + double LDS tiles (cvt at stage),
// transposed A tile (b128 broadcast reads, 2-way max), 16B-aligned rows.
// k ascends per acc -> accumulation order identical to prior rounds (bit-exact).
template<typename TA>
__global__ __launch_bounds__(256) void gemm_k(const TA* __restrict__ A, const float* __restrict__ W,
                                              double* __restrict__ Out, int n){
  __shared__ double As[64][34];   // transposed [row][k]; 34*8=272=17*16 -> aligned, 2-way only
  __shared__ double Bs[32][68];   // [k][col]; 68*8=544=34*16 -> aligned
  const int tid = threadIdx.x;
  const int r0 = blockIdx.x*64, c0 = blockIdx.y*64;
  const int ty = tid>>4, tx = tid&15;
  double acc[4][4] = {};
  for (int k0 = 0; k0 < 256; k0 += 32){
    int kA = tid & 31, rA = tid >> 5;          // coalesced global A reads; lane-consecutive LDS writes
    #pragma unroll
    for (int i=0;i<8;i++){
      int rr = rA + i*8;
      int gr = r0 + rr;
      As[rr][kA] = (gr < n) ? (double)A[(long)gr*256 + k0 + kA] : 0.0;
    }
    int cB = tid & 63, kB = tid >> 6;          // coalesced global W reads; lane-consecutive writes
    #pragma unroll
    for (int i=0;i<8;i++){
      int kk = kB + i*4;
      Bs[kk][cB] = (double)W[(k0+kk)*256 + c0 + cB];
    }
    __syncthreads();
    #pragma unroll 4
    for (int k=0;k<32;k+=2){
      double2 a2[4], b2lo[2], b2hi[2];
      #pragma unroll
      for (int i=0;i<4;i++) a2[i] = *reinterpret_cast<const double2*>(&As[ty*4+i][k]);      // broadcast
      #pragma unroll
      for (int j=0;j<2;j++){
        b2lo[j] = *reinterpret_cast<const double2*>(&Bs[k  ][tx*4+j*2]);
        b2hi[j] = *reinterpret_cast<const double2*>(&Bs[k+1][tx*4+j*2]);
      }
      #pragma unroll
      for (int i=0;i<4;i++){
        double a0 = a2[i].x;
        acc[i][0] = fma(a0, b2lo[0].x, acc[i][0]);
        acc[i][1] = fma(a0, b2lo[0].y, acc[i][1]);
        acc[i][2] = fma(a0, b2lo[1].x, acc[i][2]);
        acc[i][3] = fma(a0, b2lo[1].y, acc[i][3]);
      }
      #pragma unroll
      for (int i=0;i<4;i++){
        double a1 = a2[i].y;
        acc[i][0] = fma(a1, b2hi[0].x, acc[i][0]);
        acc[i][1] = fma(a1, b2hi[0].y, acc[i][1]);
        acc[i][2] = fma(a1, b2hi[1].x, acc[i][2]);
        acc[i][3] = fma(a1, b2hi[1].y, acc[i][3]);
      }
    }
    __syncthreads();
  }
  #pragma unroll
  for (int i=0;i<4;i++){
    int gr = r0 + ty*4 + i;
    if (gr < n){
      #pragma unroll
      for (int j=0;j<4;j++)
        Out[(long)gr*256 + c0 + tx*4 + j] = acc[i][j];
    }
  }
}

// ---------------- attention coefficients + score projection hp = h . p ----------------
__global__ void attn_k(const double* __restrict__ Hh, const float* __restrict__ asrc,
                       const float* __restrict__ adst, const float* __restrict__ p,
                       double* __restrict__ als, double* __restrict__ ald,
                       double* __restrict__ hp){
  int i = blockIdx.x; int ch = threadIdx.x; int head = ch>>6; int lane = ch&63;
  double hv = Hh[(long)i*256 + ch];
  double vs = hv * (double)asrc[ch];
  double vd = hv * (double)adst[ch];
  double vp = hv * (double)p[ch];
  for (int off=32; off; off>>=1){
    vs += __shfl_down(vs, off); vd += __shfl_down(vd, off); vp += __shfl_down(vp, off);
  }
  if (lane == 0){ als[i*4+head] = vs; ald[i*4+head] = vd; hp[i*4+head] = vp; }
}

// init segment-max with self-loop value; zero degree array in same pass
__global__ void initm_k(const double* __restrict__ als, const double* __restrict__ ald,
                        ull* __restrict__ menc, int* __restrict__ deg, int n){
  int t = blockIdx.x*blockDim.x + threadIdx.x;
  if (t >= 4*n) return;
  menc[t] = encd(lrelu(als[t] + ald[t]));
  if (t < n) deg[t] = 0;
}

// edge max + degree count in one pass
__global__ void edgemax_k(const int* __restrict__ src, const int* __restrict__ dst,
                          const int* __restrict__ msk, const double* __restrict__ als,
                          const double* __restrict__ ald, ull* __restrict__ menc,
                          int* __restrict__ deg, int e){
  int t = blockIdx.x*blockDim.x + threadIdx.x;
  if (t >= e) return;
  if (msk && !msk[t]) return;
  int s = src[t], d = dst[t];
  atomicAdd(&deg[d], 1);
  #pragma unroll
  for (int h=0;h<4;h++){
    double ev = lrelu(als[s*4+h] + ald[d*4+h]);
    atomicMax(&menc[d*4+h], encd(ev));
  }
}

__global__ void wself_k(const double* __restrict__ als, const double* __restrict__ ald,
                        const ull* __restrict__ menc, double* __restrict__ wself, int total){
  int t = blockIdx.x*blockDim.x + threadIdx.x;
  if (t >= total) return;
  double e = lrelu(als[t] + ald[t]);
  wself[t] = exp(e - decd(menc[t]));
}

__global__ void edgew_k(const int* __restrict__ src, const int* __restrict__ dst,
                        const int* __restrict__ msk, const double* __restrict__ als,
                        const double* __restrict__ ald, const ull* __restrict__ menc,
                        double* __restrict__ wedge, int e){
  int t = blockIdx.x*blockDim.x + threadIdx.x;
  if (t >= e) return;
  int s = src[t], d = dst[t];
  bool ok = (!msk) || (msk[t] != 0);
  #pragma unroll
  for (int h=0;h<4;h++){
    double w = 0.0;
    if (ok){
      double ev = lrelu(als[s*4+h] + ald[d*4+h]);
      w = exp(ev - decd(menc[d*4+h]));
    }
    wedge[(long)t*4+h] = w;
  }
}

// ---------------- hierarchical scan (blocks of 256) ----------------
__global__ __launch_bounds__(256) void scanA_k(int* __restrict__ a, int* __restrict__ btot, int n){
  __shared__ int s[256];
  int g = blockIdx.x*256 + threadIdx.x;
  s[threadIdx.x] = (g < n) ? a[g] : 0;
  __syncthreads();
  for (int off=1; off<256; off<<=1){
    int t = (threadIdx.x >= off) ? s[threadIdx.x-off] : 0;
    __syncthreads();
    s[threadIdx.x] += t;
    __syncthreads();
  }
  if (g < n) a[g] = s[threadIdx.x];
  if (threadIdx.x == 255) btot[blockIdx.x] = s[255];
}

__global__ __launch_bounds__(1024) void scanB_k(int* __restrict__ btot, int nb){
  __shared__ int s[1024];
  int t = threadIdx.x;
  s[t] = (t < nb) ? btot[t] : 0;
  __syncthreads();
  for (int off=1; off<1024; off<<=1){
    int v = (t >= off) ? s[t-off] : 0;
    __syncthreads();
    s[t] += v;
    __syncthreads();
  }
  if (t < nb) btot[t] = s[t];
}

__global__ void scanC_rowptr_k(const int* __restrict__ a, const int* __restrict__ btot,
                               int* __restrict__ rowptr, int* __restrict__ cursor, int n){
  int g = blockIdx.x*blockDim.x + threadIdx.x;
  if (g >= n) return;
  int B = g >> 8;
  int off = (B > 0) ? btot[B-1] : 0;
  rowptr[g+1] = a[g] + off;
  cursor[g] = 0;
  if (g == 0) rowptr[0] = 0;
}

__global__ void scanC_above_k(const int* __restrict__ a, const int* __restrict__ btot,
                              int* __restrict__ habove, int nelems, int nbins){
  int g = blockIdx.x*blockDim.x + threadIdx.x;
  if (g >= nbins) return;
  int B = g >> 8;
  int off = (B > 0) ? btot[B-1] : 0;
  habove[g] = nelems - (a[g] + off);
}

__global__ void place_k(const int* __restrict__ dst, const int* __restrict__ msk,
                        const int* __restrict__ rowptr, int* __restrict__ cursor,
                        int* __restrict__ csr, int e){
  int t = blockIdx.x*blockDim.x + threadIdx.x;
  if (t >= e) return;
  if (msk && !msk[t]) return;
  int d = dst[t];
  int slot = atomicAdd(&cursor[d], 1);
  csr[rowptr[d] + slot] = t;
}

// ---------------- score via precomputed hp ----------------
__global__ void score_csr_k(const double* __restrict__ hp, const double* __restrict__ wed,
                            const double* __restrict__ wse, const int* __restrict__ srcA,
                            const int* __restrict__ rowptr, const int* __restrict__ csr,
                            const double* __restrict__ nrmbp, double* __restrict__ z, int n){
  int g = blockIdx.x*blockDim.x + threadIdx.x;
  int i = g>>2, h = g&3;
  if (i >= n) return;
  double ws = wse[i*4+h];
  double acc = ws * hp[(long)i*4+h];
  double den = ws;
  int b = rowptr[i], e = rowptr[i+1];
  for (int t=b; t<e; t++){
    int eid = csr[t]; int s = srcA[eid];
    double w = wed[(long)eid*4+h];
    acc = fma(w, hp[(long)s*4+h], acc);
    den += w;
  }
  double part = acc/den;
  part += __shfl_xor(part, 1);
  part += __shfl_xor(part, 2);
  if (h == 0) z[i] = (part + nrmbp[1]) / nrmbp[0];
}

// full row of X for node i (one channel per thread); deterministic denominator
__device__ __forceinline__ double gat_row(const double* __restrict__ Hh, const int* __restrict__ srcA,
                                          const int* __restrict__ rowptr, const int* __restrict__ csr,
                                          const double* __restrict__ wed, const double* __restrict__ wse,
                                          const float* __restrict__ bias, int i, int ch, int h){
  double acc = wse[i*4+h] * Hh[(long)i*256 + ch];
  double dsum = wse[i*4+h];
  int b = rowptr[i], e = rowptr[i+1];
  for (int t=b; t<e; t++){
    int eid = csr[t]; int s = srcA[eid];
    double w = wed[(long)eid*4+h];
    acc  = fma(w, Hh[(long)s*256 + ch], acc);
    dsum += w;
  }
  return acc/dsum + (double)bias[ch];
}

__global__ void aggr_gate_k(const double* __restrict__ Hh, const int* __restrict__ srcA,
                            const int* __restrict__ rowptr, const int* __restrict__ csr,
                            const double* __restrict__ wed, const double* __restrict__ wse,
                            const float* __restrict__ bias, const int* __restrict__ perm,
                            const double* __restrict__ scs, double* __restrict__ Xi){
  int r = blockIdx.x, ch = threadIdx.x, h = ch>>6;
  int i = perm[r];
  double row = gat_row(Hh, srcA, rowptr, csr, wed, wse, bias, i, ch, h);
  double v = row * scs[r];
  Xi[(long)r*256 + ch] = v > 0.0 ? v : 0.0;
}

__global__ void aggr_final_k(const double* __restrict__ Hh, const int* __restrict__ srcA,
                             const int* __restrict__ rowptr, const int* __restrict__ csr,
                             const double* __restrict__ wed, const double* __restrict__ wse,
                             const float* __restrict__ bias, const int* __restrict__ perm,
                             const double* __restrict__ scs, float* __restrict__ out){
  int r = blockIdx.x, ch = threadIdx.x, h = ch>>6;
  int i = perm[r];
  double row = gat_row(Hh, srcA, rowptr, csr, wed, wse, bias, i, ch, h);
  double v = row * scs[r];
  out[(long)r*256 + ch] = (float)(v > 0.0 ? v : 0.0);
}

// ||p|| and b.p
__global__ void pnorm_k(const float* __restrict__ p, const float* __restrict__ bias,
                        double* __restrict__ nrmbp){
  __shared__ double ws_[8];
  int tid = threadIdx.x;
  double pv = (double)p[tid];
  double v = pv*pv;
  double w = (double)bias[tid]*pv;
  for (int off=32; off; off>>=1){ v += __shfl_down(v, off); w += __shfl_down(w, off); }
  if ((tid&63)==0){ ws_[tid>>6] = v; ws_[4+(tid>>6)] = w; }
  __syncthreads();
  if (tid == 0){
    nrmbp[0] = sqrt(ws_[0]+ws_[1]+ws_[2]+ws_[3]);
    nrmbp[1] = ws_[4]+ws_[5]+ws_[6]+ws_[7];
  }
}

// ---------------- bucket-based exact ranking ----------------
__global__ void keyhist_k(const double* __restrict__ z, ull* __restrict__ k64,
                          int* __restrict__ hist, int n){
  int i = blockIdx.x*blockDim.x + threadIdx.x;
  if (i >= n) return;
  ull e = encd(z[i]);
  k64[i] = e;
  atomicAdd(&hist[(int)(e >> BSHIFT)], 1);
}

__global__ void bplace_k(const ull* __restrict__ k64, const int* __restrict__ habove,
                         int* __restrict__ cur, int* __restrict__ isort, int n){
  int i = blockIdx.x*blockDim.x + threadIdx.x;
  if (i >= n) return;
  int b = (int)(k64[i] >> BSHIFT);
  int slot = atomicAdd(&cur[b], 1);
  isort[habove[b] + slot] = i;
}

__global__ void brank_k(const ull* __restrict__ k64, const int* __restrict__ habove,
                        const int* __restrict__ isort, int* __restrict__ rank, int n){
  int i = blockIdx.x*blockDim.x + threadIdx.x;
  if (i >= n) return;
  ull ki = k64[i];
  int b = (int)(ki >> BSHIFT);
  int lo = habove[b];
  int hi = (b > 0) ? habove[b-1] : n;
  int cnt = 0;
  for (int t = lo; t < hi; t++){
    int j = isort[t];
    ull kj = k64[j];
    cnt += ((kj > ki) || (kj == ki && j < i)) ? 1 : 0;
  }
  rank[i] = lo + cnt;
}

__global__ void scatter_k(const double* __restrict__ z, const int* __restrict__ rank,
                          int* __restrict__ perm, int* __restrict__ inv,
                          double* __restrict__ scs, int n, int k){
  int i = blockIdx.x*blockDim.x + threadIdx.x;
  if (i >= n) return;
  int r = rank[i];
  inv[i] = (r < k) ? r : -1;
  if (r < k){ perm[r] = i; scs[r] = tanh(z[i]); }
}

__global__ void reindex_k(const int* __restrict__ src, const int* __restrict__ dst,
                          const int* __restrict__ inv,
                          int* __restrict__ ns, int* __restrict__ nd, int* __restrict__ nmsk, int e){
  int t = blockIdx.x*blockDim.x + threadIdx.x;
  if (t >= e) return;
  int a = inv[src[t]], b = inv[dst[t]];
  int ok = (a >= 0) && (b >= 0);
  ns[t] = ok ? a : 0; nd[t] = ok ? b : 0; nmsk[t] = ok;
}

__global__ void finedge_k(const int* __restrict__ ns, const int* __restrict__ nd,
                          const int* __restrict__ msk, const int* __restrict__ inv,
                          float* __restrict__ osrc, float* __restrict__ odst,
                          float* __restrict__ omsk, int e){
  int t = blockIdx.x*blockDim.x + threadIdx.x;
  if (t >= e) return;
  int a = inv[ns[t]], b = inv[nd[t]];
  int ok = msk[t] && (a >= 0) && (b >= 0);
  osrc[t] = (float)(ok ? a : 0);
  odst[t] = (float)(ok ? b : 0);
  omsk[t] = ok ? 1.0f : 0.0f;
}

__global__ void zerof_k(float* __restrict__ o, int n){
  int t = blockIdx.x*blockDim.x + threadIdx.x;
  if (t < n) o[t] = 0.0f;
}

extern "C" void kernel_launch(void* const* d_in, const int* in_sizes, int n_in,
                              void* d_out, int out_size, void* d_ws, size_t ws_size,
                              hipStream_t stream){
  (void)in_sizes; (void)n_in; (void)out_size; (void)ws_size;
  const float* x   = (const float*)d_in[0];
  const int*   ei  = (const int*)d_in[1];
  const float* W1  = (const float*)d_in[3];
  const float* as1 = (const float*)d_in[4];
  const float* ad1 = (const float*)d_in[5];
  const float* b1  = (const float*)d_in[6];
  const float* p1  = (const float*)d_in[7];
  const float* W2  = (const float*)d_in[8];
  const float* as2 = (const float*)d_in[9];
  const float* ad2 = (const float*)d_in[10];
  const float* b2  = (const float*)d_in[11];
  const float* p2  = (const float*)d_in[12];
  const int* src0 = ei;
  const int* dst0 = ei + EE;

  char* cur_ = (char*)d_ws;
  auto take = [&](size_t bytes)->void*{ void* p = (void*)cur_; cur_ += (bytes + 255) & ~(size_t)255; return p; };
  double* bufA = (double*)take((size_t)NN1*256*8);   // Hh1; later Hh2
  double* Xi   = (double*)take((size_t)KK1*256*8);
  double* als  = (double*)take((size_t)NN1*4*8);     // aliased by hist during pooling
  double* ald  = (double*)take((size_t)NN1*4*8);     // aliased by habove
  ull*    menc = (ull*)   take((size_t)NN1*4*8);     // aliased by bcur
  double* wse  = (double*)take((size_t)NN1*4*8);
  double* hp   = (double*)take((size_t)NN1*4*8);
  double* wed  = (double*)take((size_t)EE*4*8);
  double* sco  = (double*)take((size_t)NN1*8);
  double* scs  = (double*)take((size_t)KK1*8);
  double* nrm  = (double*)take(256);
  ull*    k64  = (ull*)   take((size_t)NN1*8);
  int* isort= (int*)take((size_t)NN1*4);
  int* rnk  = (int*)take((size_t)NN1*4);
  int* prm  = (int*)take((size_t)KK1*4);
  int* inv  = (int*)take((size_t)NN1*4);
  int* deg  = (int*)take((size_t)(NN1+1)*4);
  int* rwp  = (int*)take((size_t)(NN1+1)*4);
  int* cursr= (int*)take((size_t)NN1*4);
  int* csr  = (int*)take((size_t)EE*4);
  int* ns   = (int*)take((size_t)EE*4);
  int* nd   = (int*)take((size_t)EE*4);
  int* mk2  = (int*)take((size_t)EE*4);
  int* btot = (int*)take((size_t)1024*4);

  // bucket-rank arrays alias als/ald/menc (dead once wed/wse are built)
  int* hist   = (int*)als;
  int* habove = (int*)ald;
  int* bcur   = (int*)menc;

  double* Hh1 = bufA;
  double* Hh2 = bufA;

  float* out = (float*)d_out;
  float* o_x = out;
  float* o_s = out + (size_t)KK2*256;
  float* o_d = o_s + EE;
  float* o_m = o_d + EE;
  float* o_b = o_m + EE;

  // ---------------- stage 1: GATConv on (N1, E) ----------------
  gemm_k<float><<<dim3(CDIV(NN1,64),4),256,0,stream>>>(x, W1, Hh1, NN1);
  attn_k<<<NN1,256,0,stream>>>(Hh1, as1, ad1, p1, als, ald, hp);
  initm_k<<<CDIV(NN1*4,256),256,0,stream>>>(als, ald, menc, deg, NN1);
  edgemax_k<<<CDIV(EE,256),256,0,stream>>>(src0, dst0, nullptr, als, ald, menc, deg, EE);
  wself_k<<<CDIV(NN1*4,256),256,0,stream>>>(als, ald, menc, wse, NN1*4);
  edgew_k<<<CDIV(EE,256),256,0,stream>>>(src0, dst0, nullptr, als, ald, menc, wed, EE);
  scanA_k<<<CDIV(NN1,256),256,0,stream>>>(deg, btot, NN1);
  scanB_k<<<1,1024,0,stream>>>(btot, CDIV(NN1,256));
  scanC_rowptr_k<<<CDIV(NN1,256),256,0,stream>>>(deg, btot, rwp, cursr, NN1);
  place_k<<<CDIV(EE,256),256,0,stream>>>(dst0, nullptr, rwp, cursr, csr, EE);

  // ---------------- pool 1 ----------------
  pnorm_k<<<1,256,0,stream>>>(p1, b1, nrm);
  score_csr_k<<<CDIV(NN1*4,256),256,0,stream>>>(hp, wed, wse, src0, rwp, csr, nrm, sco, NN1);
  zero2_k<<<NB/256,256,0,stream>>>(hist, bcur, NB);
  keyhist_k<<<CDIV(NN1,256),256,0,stream>>>(sco, k64, hist, NN1);
  scanA_k<<<NB/256,256,0,stream>>>(hist, btot, NB);
  scanB_k<<<1,1024,0,stream>>>(btot, NB/256);
  scanC_above_k<<<NB/256,256,0,stream>>>(hist, btot, habove, NN1, NB);
  bplace_k<<<CDIV(NN1,256),256,0,stream>>>(k64, habove, bcur, isort, NN1);
  brank_k<<<CDIV(NN1,256),256,0,stream>>>(k64, habove, isort, rnk, NN1);
  scatter_k<<<CDIV(NN1,256),256,0,stream>>>(sco, rnk, prm, inv, scs, NN1, KK1);
  aggr_gate_k<<<KK1,256,0,stream>>>(Hh1, src0, rwp, csr, wed, wse, b1, prm, scs, Xi);
  reindex_k<<<CDIV(EE,256),256,0,stream>>>(src0, dst0, inv, ns, nd, mk2, EE);

  // ---------------- stage 2: GATConv on (K1, masked E) ----------------
  gemm_k<double><<<dim3(CDIV(KK1,64),4),256,0,stream>>>(Xi, W2, Hh2, KK1);
  attn_k<<<KK1,256,0,stream>>>(Hh2, as2, ad2, p2, als, ald, hp);
  initm_k<<<CDIV(KK1*4,256),256,0,stream>>>(als, ald, menc, deg, KK1);
  edgemax_k<<<CDIV(EE,256),256,0,stream>>>(ns, nd, mk2, als, ald, menc, deg, EE);
  wself_k<<<CDIV(KK1*4,256),256,0,stream>>>(als, ald, menc, wse, KK1*4);
  edgew_k<<<CDIV(EE,256),256,0,stream>>>(ns, nd, mk2, als, ald, menc, wed, EE);
  scanA_k<<<CDIV(KK1,256),256,0,stream>>>(deg, btot, KK1);
  scanB_k<<<1,1024,0,stream>>>(btot, CDIV(KK1,256));
  scanC_rowptr_k<<<CDIV(KK1,256),256,0,stream>>>(deg, btot, rwp, cursr, KK1);
  place_k<<<CDIV(EE,256),256,0,stream>>>(nd, mk2, rwp, cursr, csr, EE);

  // ---------------- pool 2 + outputs ----------------
  pnorm_k<<<1,256,0,stream>>>(p2, b2, nrm);
  score_csr_k<<<CDIV(KK1*4,256),256,0,stream>>>(hp, wed, wse, ns, rwp, csr, nrm, sco, KK1);
  zero2_k<<<NB/256,256,0,stream>>>(hist, bcur, NB);
  keyhist_k<<<CDIV(KK1,256),256,0,stream>>>(sco, k64, hist, KK1);
  scanA_k<<<NB/256,256,0,stream>>>(hist, btot, NB);
  scanB_k<<<1,1024,0,stream>>>(btot, NB/256);
  scanC_above_k<<<NB/256,256,0,stream>>>(hist, btot, habove, KK1, NB);
  bplace_k<<<CDIV(KK1,256),256,0,stream>>>(k64, habove, bcur, isort, KK1);
  brank_k<<<CDIV(KK1,256),256,0,stream>>>(k64, habove, isort, rnk, KK1);
  scatter_k<<<CDIV(KK1,256),256,0,stream>>>(sco, rnk, prm, inv, scs, KK1, KK2);
  aggr_final_k<<<KK2,256,0,stream>>>(Hh2, ns, rwp, csr, wed, wse, b2, prm, scs, o_x);
  finedge_k<<<CDIV(EE,256),256,0,stream>>>(ns, nd, mk2, inv, o_s, o_d, o_m, EE);
  zerof_k<<<CDIV(KK2,256),256,0,stream>>>(o_b, KK2);
}

// Round 8
// 991.211 us; speedup vs baseline: 1.2024x; 1.0869x over previous
//
#include <hip/hip_runtime.h>
#include <math.h>

typedef unsigned long long ull;

#define NN1 50000
#define EE  600000
#define KK1 25000
#define KK2 12500

#define NB (1<<18)      // rank buckets
#define BSHIFT 46       // 64-18

#define CDIV(a,b) (((a)+(b)-1)/(b))

__device__ __forceinline__ ull encd(double d){
  ull u = (ull)__double_as_longlong(d);
  return (u & 0x8000000000000000ULL) ? ~u : (u | 0x8000000000000000ULL);
}
__device__ __forceinline__ double decd(ull u){
  ull v = (u & 0x8000000000000000ULL) ? (u & 0x7FFFFFFFFFFFFFFFULL) : ~u;
  return __longlong_as_double((long long)v);
}
__device__ __forceinline__ double lrelu(double z){ return z > 0.0 ? z : 0.2*z; }

__global__ void zero2_k(int* __restrict__ a, int* __restrict__ b, int n){
  int t = blockIdx.x*blockDim.x + threadIdx.x;
  if (t < n){ a[t] = 0; b[t] = 0; }
}

// ---------------- Q = [W.a_src | W.a_dst | W.p_heads] : [256][12] f64 ----------------
__global__ void prepq_k(const float* __restrict__ W, const float* __restrict__ as,
                        const float* __restrict__ ad, const float* __restrict__ p,
                        double* __restrict__ Q){
  int k = blockIdx.x; int ch = threadIdx.x; int head = ch>>6; int lane = ch&63;
  double w = (double)W[k*256 + ch];
  double vs = w*(double)as[ch], vd = w*(double)ad[ch], vp = w*(double)p[ch];
  for (int off=32; off; off>>=1){
    vs += __shfl_down(vs,off); vd += __shfl_down(vd,off); vp += __shfl_down(vp,off);
  }
  if (lane==0){ Q[k*12+head]=vs; Q[k*12+4+head]=vd; Q[k*12+8+head]=vp; }
}

// ---------------- matvec: als/ald/hp = A[n,256] @ Q[256,12], f64 ----------------
template<typename TA>
__global__ __launch_bounds__(256) void matvec_k(const TA* __restrict__ A, const double* __restrict__ Q,
                                                double* __restrict__ als, double* __restrict__ ald,
                                                double* __restrict__ hp, int n){
  __shared__ double Qs[256][12];
  __shared__ TA Xs[64][65];
  int tid = threadIdx.x;
  for (int t = tid; t < 3072; t += 256) ((double*)Qs)[t] = Q[t];
  int row = tid & 63, cg = tid >> 6;
  int r0 = blockIdx.x*64;
  double a0=0, a1=0, a2=0;
  for (int k0=0; k0<256; k0+=64){
    int kk = tid & 63, rs = tid >> 6;
    #pragma unroll
    for (int i=0;i<16;i++){
      int rr = rs + i*4; int gr = r0 + rr;
      Xs[rr][kk] = (gr < n) ? A[(long)gr*256 + k0 + kk] : (TA)0;
    }
    __syncthreads();
    #pragma unroll 8
    for (int k=0;k<64;k++){
      double a = (double)Xs[row][k];
      a0 = fma(a, Qs[k0+k][cg*3+0], a0);
      a1 = fma(a, Qs[k0+k][cg*3+1], a1);
      a2 = fma(a, Qs[k0+k][cg*3+2], a2);
    }
    __syncthreads();
  }
  int gr = r0 + row;
  if (gr < n){
    double v[3] = {a0,a1,a2};
    #pragma unroll
    for (int j=0;j<3;j++){
      int q = cg*3+j;
      if (q<4)      als[gr*4+q]   = v[j];
      else if (q<8) ald[gr*4+q-4] = v[j];
      else          hp[gr*4+q-8]  = v[j];
    }
  }
}

// init segment-max with self-loop value; zero degree array in same pass
__global__ void initm_k(const double* __restrict__ als, const double* __restrict__ ald,
                        ull* __restrict__ menc, int* __restrict__ deg, int n){
  int t = blockIdx.x*blockDim.x + threadIdx.x;
  if (t >= 4*n) return;
  menc[t] = encd(lrelu(als[t] + ald[t]));
  if (t < n) deg[t] = 0;
}

// edge max + degree count in one pass
__global__ void edgemax_k(const int* __restrict__ src, const int* __restrict__ dst,
                          const int* __restrict__ msk, const double* __restrict__ als,
                          const double* __restrict__ ald, ull* __restrict__ menc,
                          int* __restrict__ deg, int e){
  int t = blockIdx.x*blockDim.x + threadIdx.x;
  if (t >= e) return;
  if (msk && !msk[t]) return;
  int s = src[t], d = dst[t];
  atomicAdd(&deg[d], 1);
  #pragma unroll
  for (int h=0;h<4;h++){
    double ev = lrelu(als[s*4+h] + ald[d*4+h]);
    atomicMax(&menc[d*4+h], encd(ev));
  }
}

// edge weights + (fused) self weights
__global__ void edgew_k(const int* __restrict__ src, const int* __restrict__ dst,
                        const int* __restrict__ msk, const double* __restrict__ als,
                        const double* __restrict__ ald, const ull* __restrict__ menc,
                        double* __restrict__ wedge, double* __restrict__ wself,
                        int e, int n4){
  int t = blockIdx.x*blockDim.x + threadIdx.x;
  if (t < n4){
    double ev = lrelu(als[t] + ald[t]);
    wself[t] = exp(ev - decd(menc[t]));
  }
  if (t >= e) return;
  int s = src[t], d = dst[t];
  bool ok = (!msk) || (msk[t] != 0);
  #pragma unroll
  for (int h=0;h<4;h++){
    double w = 0.0;
    if (ok){
      double ev = lrelu(als[s*4+h] + ald[d*4+h]);
      w = exp(ev - decd(menc[d*4+h]));
    }
    wedge[(long)t*4+h] = w;
  }
}

// ---------------- hierarchical scan (blocks of 256) ----------------
__global__ __launch_bounds__(256) void scanA_k(int* __restrict__ a, int* __restrict__ btot, int n){
  __shared__ int s[256];
  int g = blockIdx.x*256 + threadIdx.x;
  s[threadIdx.x] = (g < n) ? a[g] : 0;
  __syncthreads();
  for (int off=1; off<256; off<<=1){
    int t = (threadIdx.x >= off) ? s[threadIdx.x-off] : 0;
    __syncthreads();
    s[threadIdx.x] += t;
    __syncthreads();
  }
  if (g < n) a[g] = s[threadIdx.x];
  if (threadIdx.x == 255) btot[blockIdx.x] = s[255];
}

__global__ __launch_bounds__(1024) void scanB_k(int* __restrict__ btot, int nb){
  __shared__ int s[1024];
  int t = threadIdx.x;
  s[t] = (t < nb) ? btot[t] : 0;
  __syncthreads();
  for (int off=1; off<1024; off<<=1){
    int v = (t >= off) ? s[t-off] : 0;
    __syncthreads();
    s[t] += v;
    __syncthreads();
  }
  if (t < nb) btot[t] = s[t];
}

__global__ void scanC_rowptr_k(const int* __restrict__ a, const int* __restrict__ btot,
                               int* __restrict__ rowptr, int* __restrict__ cursor, int n){
  int g = blockIdx.x*blockDim.x + threadIdx.x;
  if (g >= n) return;
  int B = g >> 8;
  int off = (B > 0) ? btot[B-1] : 0;
  rowptr[g+1] = a[g] + off;
  cursor[g] = 0;
  if (g == 0) rowptr[0] = 0;
}

__global__ void scanC_above_k(const int* __restrict__ a, const int* __restrict__ btot,
                              int* __restrict__ habove, int nelems, int nbins){
  int g = blockIdx.x*blockDim.x + threadIdx.x;
  if (g >= nbins) return;
  int B = g >> 8;
  int off = (B > 0) ? btot[B-1] : 0;
  habove[g] = nelems - (a[g] + off);
}

__global__ void place_k(const int* __restrict__ dst, const int* __restrict__ msk,
                        const int* __restrict__ rowptr, int* __restrict__ cursor,
                        int* __restrict__ csr, int e){
  int t = blockIdx.x*blockDim.x + threadIdx.x;
  if (t >= e) return;
  if (msk && !msk[t]) return;
  int d = dst[t];
  int slot = atomicAdd(&cursor[d], 1);
  csr[rowptr[d] + slot] = t;
}

// ---------------- score via precomputed hp ----------------
__global__ void score_csr_k(const double* __restrict__ hp, const double* __restrict__ wed,
                            const double* __restrict__ wse, const int* __restrict__ srcA,
                            const int* __restrict__ rowptr, const int* __restrict__ csr,
                            const double* __restrict__ nrmbp, double* __restrict__ z, int n){
  int g = blockIdx.x*blockDim.x + threadIdx.x;
  int i = g>>2, h = g&3;
  if (i >= n) return;
  double ws = wse[i*4+h];
  double acc = ws * hp[(long)i*4+h];
  double den = ws;
  int b = rowptr[i], e = rowptr[i+1];
  for (int t=b; t<e; t++){
    int eid = csr[t]; int s = srcA[eid];
    double w = wed[(long)eid*4+h];
    acc = fma(w, hp[(long)s*4+h], acc);
    den += w;
  }
  double part = acc/den;
  part += __shfl_xor(part, 1);
  part += __shfl_xor(part, 2);
  if (h == 0) z[i] = (part + nrmbp[1]) / nrmbp[0];
}

// ---------------- per-head aggregation of raw features for kept nodes ----------------
// Xagg[r][h][k] = ( wse_h*X[i,k] + sum_e w_e,h*X[src_e,k] ) / D_h   (self first = old order)
template<typename TA>
__global__ void aggx4_k(const TA* __restrict__ X, const int* __restrict__ prm,
                        const int* __restrict__ srcA, const int* __restrict__ rowptr,
                        const int* __restrict__ csr, const double* __restrict__ wed,
                        const double* __restrict__ wse, double* __restrict__ Xagg){
  int r = blockIdx.x, k = threadIdx.x;
  int i = prm[r];
  double w0 = wse[i*4+0], w1 = wse[i*4+1], w2 = wse[i*4+2], w3 = wse[i*4+3];
  double xv = (double)X[(long)i*256 + k];
  double a0=w0*xv, a1=w1*xv, a2=w2*xv, a3=w3*xv;
  double d0=w0, d1=w1, d2=w2, d3=w3;
  int b = rowptr[i], e = rowptr[i+1];
  for (int t=b; t<e; t++){
    int eid = csr[t]; int s = srcA[eid];
    double sv = (double)X[(long)s*256 + k];
    double e0=wed[(long)eid*4+0], e1=wed[(long)eid*4+1];
    double e2=wed[(long)eid*4+2], e3=wed[(long)eid*4+3];
    a0=fma(e0,sv,a0); a1=fma(e1,sv,a1); a2=fma(e2,sv,a2); a3=fma(e3,sv,a3);
    d0+=e0; d1+=e1; d2+=e2; d3+=e3;
  }
  long base = (long)r*1024 + k;
  Xagg[base      ] = a0/d0;
  Xagg[base + 256] = a1/d1;
  Xagg[base + 512] = a2/d2;
  Xagg[base + 768] = a3/d3;
}

// ---------------- GEMM + epilogue: Out[r][c] = relu(scs[r]*(Xagg_h@W_h + b)) ----------------
// blockIdx.y = head; A row = Xagg[r][head][0..255]; cols c0=head*64..+63.
template<typename TO>
__global__ __launch_bounds__(256) void gemmE_k(const double* __restrict__ A,
                                               const float* __restrict__ W,
                                               const float* __restrict__ bias,
                                               const double* __restrict__ scs,
                                               TO* __restrict__ Out, int n){
  __shared__ double As[64][34];   // [row][k], 34*8=272 -> 16B aligned, 2-way max
  __shared__ double Bs[32][68];   // [k][col]
  int tid = threadIdx.x;
  int r0 = blockIdx.x*64; int head = blockIdx.y; int c0 = head*64;
  int ty = tid>>4, tx = tid&15;
  double acc[4][4] = {};
  for (int k0=0; k0<256; k0+=32){
    int kA = tid&31, rA = tid>>5;
    #pragma unroll
    for (int i=0;i<8;i++){
      int rr = rA + i*8; int gr = r0+rr;
      As[rr][kA] = (gr<n) ? A[(long)gr*1024 + head*256 + k0 + kA] : 0.0;
    }
    int cB = tid&63, kB = tid>>6;
    #pragma unroll
    for (int i=0;i<8;i++){
      int kk = kB + i*4;
      Bs[kk][cB] = (double)W[(k0+kk)*256 + c0 + cB];
    }
    __syncthreads();
    #pragma unroll 4
    for (int k=0;k<32;k+=2){
      double2 a2[4];
      double blo[4], bhi[4];
      #pragma unroll
      for (int i=0;i<4;i++) a2[i] = *reinterpret_cast<const double2*>(&As[ty*4+i][k]);
      #pragma unroll
      for (int j=0;j<4;j++){ blo[j] = Bs[k][tx+16*j]; bhi[j] = Bs[k+1][tx+16*j]; }
      #pragma unroll
      for (int i=0;i<4;i++)
        #pragma unroll
        for (int j=0;j<4;j++) acc[i][j] = fma(a2[i].x, blo[j], acc[i][j]);
      #pragma unroll
      for (int i=0;i<4;i++)
        #pragma unroll
        for (int j=0;j<4;j++) acc[i][j] = fma(a2[i].y, bhi[j], acc[i][j]);
    }
    __syncthreads();
  }
  #pragma unroll
  for (int i=0;i<4;i++){
    int gr = r0 + ty*4 + i;
    if (gr < n){
      double s = scs[gr];
      #pragma unroll
      for (int j=0;j<4;j++){
        int c = c0 + tx + 16*j;
        double v = (acc[i][j] + (double)bias[c]) * s;
        Out[(long)gr*256 + c] = (TO)(v > 0.0 ? v : 0.0);
      }
    }
  }
}

// ||p|| and b.p
__global__ void pnorm_k(const float* __restrict__ p, const float* __restrict__ bias,
                        double* __restrict__ nrmbp){
  __shared__ double ws_[8];
  int tid = threadIdx.x;
  double pv = (double)p[tid];
  double v = pv*pv;
  double w = (double)bias[tid]*pv;
  for (int off=32; off; off>>=1){ v += __shfl_down(v, off); w += __shfl_down(w, off); }
  if ((tid&63)==0){ ws_[tid>>6] = v; ws_[4+(tid>>6)] = w; }
  __syncthreads();
  if (tid == 0){
    nrmbp[0] = sqrt(ws_[0]+ws_[1]+ws_[2]+ws_[3]);
    nrmbp[1] = ws_[4]+ws_[5]+ws_[6]+ws_[7];
  }
}

// ---------------- bucket-based exact ranking ----------------
__global__ void keyhist_k(const double* __restrict__ z, ull* __restrict__ k64,
                          int* __restrict__ hist, int n){
  int i = blockIdx.x*blockDim.x + threadIdx.x;
  if (i >= n) return;
  ull e = encd(z[i]);
  k64[i] = e;
  atomicAdd(&hist[(int)(e >> BSHIFT)], 1);
}

__global__ void bplace_k(const ull* __restrict__ k64, const int* __restrict__ habove,
                         int* __restrict__ cur, int* __restrict__ isort, int n){
  int i = blockIdx.x*blockDim.x + threadIdx.x;
  if (i >= n) return;
  int b = (int)(k64[i] >> BSHIFT);
  int slot = atomicAdd(&cur[b], 1);
  isort[habove[b] + slot] = i;
}

__global__ void brank_k(const ull* __restrict__ k64, const int* __restrict__ habove,
                        const int* __restrict__ isort, int* __restrict__ rank, int n){
  int i = blockIdx.x*blockDim.x + threadIdx.x;
  if (i >= n) return;
  ull ki = k64[i];
  int b = (int)(ki >> BSHIFT);
  int lo = habove[b];
  int hi = (b > 0) ? habove[b-1] : n;
  int cnt = 0;
  for (int t = lo; t < hi; t++){
    int j = isort[t];
    ull kj = k64[j];
    cnt += ((kj > ki) || (kj == ki && j < i)) ? 1 : 0;
  }
  rank[i] = lo + cnt;
}

__global__ void scatter_k(const double* __restrict__ z, const int* __restrict__ rank,
                          int* __restrict__ perm, int* __restrict__ inv,
                          double* __restrict__ scs, int n, int k){
  int i = blockIdx.x*blockDim.x + threadIdx.x;
  if (i >= n) return;
  int r = rank[i];
  inv[i] = (r < k) ? r : -1;
  if (r < k){ perm[r] = i; scs[r] = tanh(z[i]); }
}

__global__ void reindex_k(const int* __restrict__ src, const int* __restrict__ dst,
                          const int* __restrict__ inv,
                          int* __restrict__ ns, int* __restrict__ nd, int* __restrict__ nmsk, int e){
  int t = blockIdx.x*blockDim.x + threadIdx.x;
  if (t >= e) return;
  int a = inv[src[t]], b = inv[dst[t]];
  int ok = (a >= 0) && (b >= 0);
  ns[t] = ok ? a : 0; nd[t] = ok ? b : 0; nmsk[t] = ok;
}

__global__ void finedge_k(const int* __restrict__ ns, const int* __restrict__ nd,
                          const int* __restrict__ msk, const int* __restrict__ inv,
                          float* __restrict__ osrc, float* __restrict__ odst,
                          float* __restrict__ omsk, int e){
  int t = blockIdx.x*blockDim.x + threadIdx.x;
  if (t >= e) return;
  int a = inv[ns[t]], b = inv[nd[t]];
  int ok = msk[t] && (a >= 0) && (b >= 0);
  osrc[t] = (float)(ok ? a : 0);
  odst[t] = (float)(ok ? b : 0);
  omsk[t] = ok ? 1.0f : 0.0f;
}

__global__ void zerof_k(float* __restrict__ o, int n){
  int t = blockIdx.x*blockDim.x + threadIdx.x;
  if (t < n) o[t] = 0.0f;
}

extern "C" void kernel_launch(void* const* d_in, const int* in_sizes, int n_in,
                              void* d_out, int out_size, void* d_ws, size_t ws_size,
                              hipStream_t stream){
  (void)in_sizes; (void)n_in; (void)out_size; (void)ws_size;
  const float* x   = (const float*)d_in[0];
  const int*   ei  = (const int*)d_in[1];
  const float* W1  = (const float*)d_in[3];
  const float* as1 = (const float*)d_in[4];
  const float* ad1 = (const float*)d_in[5];
  const float* b1  = (const float*)d_in[6];
  const float* p1  = (const float*)d_in[7];
  const float* W2  = (const float*)d_in[8];
  const float* as2 = (const float*)d_in[9];
  const float* ad2 = (const float*)d_in[10];
  const float* b2  = (const float*)d_in[11];
  const float* p2  = (const float*)d_in[12];
  const int* src0 = ei;
  const int* dst0 = ei + EE;

  char* cur_ = (char*)d_ws;
  auto take = [&](size_t bytes)->void*{ void* p = (void*)cur_; cur_ += (bytes + 255) & ~(size_t)255; return p; };
  double* Xagg = (double*)take((size_t)12500*1024*8);   // 102.4 MB (was Hh slot)
  double* Xi   = (double*)take((size_t)KK1*256*8);
  double* als  = (double*)take((size_t)NN1*4*8);        // aliased by hist during pooling
  double* ald  = (double*)take((size_t)NN1*4*8);        // aliased by habove
  ull*    menc = (ull*)   take((size_t)NN1*4*8);        // aliased by bcur
  double* wse  = (double*)take((size_t)NN1*4*8);
  double* hp   = (double*)take((size_t)NN1*4*8);
  double* wed  = (double*)take((size_t)EE*4*8);
  double* sco  = (double*)take((size_t)NN1*8);
  double* scs  = (double*)take((size_t)KK1*8);
  double* nrm  = (double*)take(256);
  double* Q    = (double*)take((size_t)3072*8);
  ull*    k64  = (ull*)   take((size_t)NN1*8);
  int* isort= (int*)take((size_t)NN1*4);
  int* rnk  = (int*)take((size_t)NN1*4);
  int* prm  = (int*)take((size_t)KK1*4);
  int* inv  = (int*)take((size_t)NN1*4);
  int* deg  = (int*)take((size_t)(NN1+1)*4);
  int* rwp  = (int*)take((size_t)(NN1+1)*4);
  int* cursr= (int*)take((size_t)NN1*4);
  int* csr  = (int*)take((size_t)EE*4);
  int* ns   = (int*)take((size_t)EE*4);
  int* nd   = (int*)take((size_t)EE*4);
  int* mk2  = (int*)take((size_t)EE*4);
  int* btot = (int*)take((size_t)1024*4);

  int* hist   = (int*)als;
  int* habove = (int*)ald;
  int* bcur   = (int*)menc;

  float* out = (float*)d_out;
  float* o_x = out;
  float* o_s = out + (size_t)KK2*256;
  float* o_d = o_s + EE;
  float* o_m = o_d + EE;
  float* o_b = o_m + EE;

  // ---------------- stage 1 ----------------
  prepq_k<<<256,256,0,stream>>>(W1, as1, ad1, p1, Q);
  pnorm_k<<<1,256,0,stream>>>(p1, b1, nrm);
  matvec_k<float><<<CDIV(NN1,64),256,0,stream>>>(x, Q, als, ald, hp, NN1);
  initm_k<<<CDIV(NN1*4,256),256,0,stream>>>(als, ald, menc, deg, NN1);
  edgemax_k<<<CDIV(EE,256),256,0,stream>>>(src0, dst0, nullptr, als, ald, menc, deg, EE);
  edgew_k<<<CDIV(EE,256),256,0,stream>>>(src0, dst0, nullptr, als, ald, menc, wed, wse, EE, NN1*4);
  scanA_k<<<CDIV(NN1,256),256,0,stream>>>(deg, btot, NN1);
  scanB_k<<<1,1024,0,stream>>>(btot, CDIV(NN1,256));
  scanC_rowptr_k<<<CDIV(NN1,256),256,0,stream>>>(deg, btot, rwp, cursr, NN1);
  place_k<<<CDIV(EE,256),256,0,stream>>>(dst0, nullptr, rwp, cursr, csr, EE);

  // pool 1
  score_csr_k<<<CDIV(NN1*4,256),256,0,stream>>>(hp, wed, wse, src0, rwp, csr, nrm, sco, NN1);
  zero2_k<<<NB/256,256,0,stream>>>(hist, bcur, NB);
  keyhist_k<<<CDIV(NN1,256),256,0,stream>>>(sco, k64, hist, NN1);
  scanA_k<<<NB/256,256,0,stream>>>(hist, btot, NB);
  scanB_k<<<1,1024,0,stream>>>(btot, NB/256);
  scanC_above_k<<<NB/256,256,0,stream>>>(hist, btot, habove, NN1, NB);
  bplace_k<<<CDIV(NN1,256),256,0,stream>>>(k64, habove, bcur, isort, NN1);
  brank_k<<<CDIV(NN1,256),256,0,stream>>>(k64, habove, isort, rnk, NN1);
  scatter_k<<<CDIV(NN1,256),256,0,stream>>>(sco, rnk, prm, inv, scs, NN1, KK1);

  // gated features: two chunks of 12500 kept nodes
  aggx4_k<float><<<12500,256,0,stream>>>(x, prm, src0, rwp, csr, wed, wse, Xagg);
  gemmE_k<double><<<dim3(CDIV(12500,64),4),256,0,stream>>>(Xagg, W1, b1, scs, Xi, 12500);
  aggx4_k<float><<<12500,256,0,stream>>>(x, prm+12500, src0, rwp, csr, wed, wse, Xagg);
  gemmE_k<double><<<dim3(CDIV(12500,64),4),256,0,stream>>>(Xagg, W1, b1, scs+12500,
                                                           Xi+(size_t)12500*256, 12500);
  reindex_k<<<CDIV(EE,256),256,0,stream>>>(src0, dst0, inv, ns, nd, mk2, EE);

  // ---------------- stage 2 ----------------
  prepq_k<<<256,256,0,stream>>>(W2, as2, ad2, p2, Q);
  pnorm_k<<<1,256,0,stream>>>(p2, b2, nrm);
  matvec_k<double><<<CDIV(KK1,64),256,0,stream>>>(Xi, Q, als, ald, hp, KK1);
  initm_k<<<CDIV(KK1*4,256),256,0,stream>>>(als, ald, menc, deg, KK1);
  edgemax_k<<<CDIV(EE,256),256,0,stream>>>(ns, nd, mk2, als, ald, menc, deg, EE);
  edgew_k<<<CDIV(EE,256),256,0,stream>>>(ns, nd, mk2, als, ald, menc, wed, wse, EE, KK1*4);
  scanA_k<<<CDIV(KK1,256),256,0,stream>>>(deg, btot, KK1);
  scanB_k<<<1,1024,0,stream>>>(btot, CDIV(KK1,256));
  scanC_rowptr_k<<<CDIV(KK1,256),256,0,stream>>>(deg, btot, rwp, cursr, KK1);
  place_k<<<CDIV(EE,256),256,0,stream>>>(nd, mk2, rwp, cursr, csr, EE);

  // pool 2 + outputs
  score_csr_k<<<CDIV(KK1*4,256),256,0,stream>>>(hp, wed, wse, ns, rwp, csr, nrm, sco, KK1);
  zero2_k<<<NB/256,256,0,stream>>>(hist, bcur, NB);
  keyhist_k<<<CDIV(KK1,256),256,0,stream>>>(sco, k64, hist, KK1);
  scanA_k<<<NB/256,256,0,stream>>>(hist, btot, NB);
  scanB_k<<<1,1024,0,stream>>>(btot, NB/256);
  scanC_above_k<<<NB/256,256,0,stream>>>(hist, btot, habove, KK1, NB);
  bplace_k<<<CDIV(KK1,256),256,0,stream>>>(k64, habove, bcur, isort, KK1);
  brank_k<<<CDIV(KK1,256),256,0,stream>>>(k64, habove, isort, rnk, KK1);
  scatter_k<<<CDIV(KK1,256),256,0,stream>>>(sco, rnk, prm, inv, scs, KK1, KK2);

  aggx4_k<double><<<12500,256,0,stream>>>(Xi, prm, ns, rwp, csr, wed, wse, Xagg);
  gemmE_k<float><<<dim3(CDIV(12500,64),4),256,0,stream>>>(Xagg, W2, b2, scs, o_x, 12500);
  finedge_k<<<CDIV(EE,256),256,0,stream>>>(ns, nd, mk2, inv, o_s, o_d, o_m, EE);
  zerof_k<<<CDIV(KK2,256),256,0,stream>>>(o_b, KK2);
}

// Round 9
// 793.065 us; speedup vs baseline: 1.5028x; 1.2498x over previous
//
#include <hip/hip_runtime.h>
#include <math.h>

typedef unsigned long long ull;

#define NN1 50000
#define EE  600000
#define KK1 25000
#define KK2 12500

#define NB (1<<18)      // rank buckets
#define BSHIFT 46       // 64-18

#define CDIV(a,b) (((a)+(b)-1)/(b))

__device__ __forceinline__ ull encd(double d){
  ull u = (ull)__double_as_longlong(d);
  return (u & 0x8000000000000000ULL) ? ~u : (u | 0x8000000000000000ULL);
}
__device__ __forceinline__ double lrelu(double z){ return z > 0.0 ? z : 0.2*z; }

__global__ void zeroi_k(int* __restrict__ p, int n){
  int t = blockIdx.x*blockDim.x + threadIdx.x;
  if (t < n) p[t] = 0;
}
__global__ void zero2_k(int* __restrict__ a, int* __restrict__ b, int n){
  int t = blockIdx.x*blockDim.x + threadIdx.x;
  if (t < n){ a[t] = 0; b[t] = 0; }
}

// ---------------- Q = [W.a_src | W.a_dst | W.p_heads] : [256][12] f64 ----------------
__global__ void prepq_k(const float* __restrict__ W, const float* __restrict__ as,
                        const float* __restrict__ ad, const float* __restrict__ p,
                        double* __restrict__ Q){
  int k = blockIdx.x; int ch = threadIdx.x; int head = ch>>6; int lane = ch&63;
  double w = (double)W[k*256 + ch];
  double vs = w*(double)as[ch], vd = w*(double)ad[ch], vp = w*(double)p[ch];
  for (int off=32; off; off>>=1){
    vs += __shfl_down(vs,off); vd += __shfl_down(vd,off); vp += __shfl_down(vp,off);
  }
  if (lane==0){ Q[k*12+head]=vs; Q[k*12+4+head]=vd; Q[k*12+8+head]=vp; }
}

// ---------------- matvec: als/ald/hp = A[n,256] @ Q[256,12], f64 ----------------
template<typename TA>
__global__ __launch_bounds__(256) void matvec_k(const TA* __restrict__ A, const double* __restrict__ Q,
                                                double* __restrict__ als, double* __restrict__ ald,
                                                double* __restrict__ hp, int n){
  __shared__ double Qs[256][12];
  __shared__ TA Xs[64][65];
  int tid = threadIdx.x;
  for (int t = tid; t < 3072; t += 256) ((double*)Qs)[t] = Q[t];
  int row = tid & 63, cg = tid >> 6;
  int r0 = blockIdx.x*64;
  double a0=0, a1=0, a2=0;
  for (int k0=0; k0<256; k0+=64){
    int kk = tid & 63, rs = tid >> 6;
    #pragma unroll
    for (int i=0;i<16;i++){
      int rr = rs + i*4; int gr = r0 + rr;
      Xs[rr][kk] = (gr < n) ? A[(long)gr*256 + k0 + kk] : (TA)0;
    }
    __syncthreads();
    #pragma unroll 8
    for (int k=0;k<64;k++){
      double a = (double)Xs[row][k];
      a0 = fma(a, Qs[k0+k][cg*3+0], a0);
      a1 = fma(a, Qs[k0+k][cg*3+1], a1);
      a2 = fma(a, Qs[k0+k][cg*3+2], a2);
    }
    __syncthreads();
  }
  int gr = r0 + row;
  if (gr < n){
    double v[3] = {a0,a1,a2};
    #pragma unroll
    for (int j=0;j<3;j++){
      int q = cg*3+j;
      if (q<4)      als[gr*4+q]   = v[j];
      else if (q<8) ald[gr*4+q-4] = v[j];
      else          hp[gr*4+q-8]  = v[j];
    }
  }
}

__global__ void deg_k(const int* __restrict__ dst, const int* __restrict__ msk,
                      int* __restrict__ deg, int e){
  int t = blockIdx.x*blockDim.x + threadIdx.x;
  if (t >= e) return;
  if (msk && !msk[t]) return;
  atomicAdd(&deg[dst[t]], 1);
}

// ---------------- hierarchical scan (blocks of 256) ----------------
__global__ __launch_bounds__(256) void scanA_k(int* __restrict__ a, int* __restrict__ btot, int n){
  __shared__ int s[256];
  int g = blockIdx.x*256 + threadIdx.x;
  s[threadIdx.x] = (g < n) ? a[g] : 0;
  __syncthreads();
  for (int off=1; off<256; off<<=1){
    int t = (threadIdx.x >= off) ? s[threadIdx.x-off] : 0;
    __syncthreads();
    s[threadIdx.x] += t;
    __syncthreads();
  }
  if (g < n) a[g] = s[threadIdx.x];
  if (threadIdx.x == 255) btot[blockIdx.x] = s[255];
}

__global__ __launch_bounds__(1024) void scanB_k(int* __restrict__ btot, int nb){
  __shared__ int s[1024];
  int t = threadIdx.x;
  s[t] = (t < nb) ? btot[t] : 0;
  __syncthreads();
  for (int off=1; off<1024; off<<=1){
    int v = (t >= off) ? s[t-off] : 0;
    __syncthreads();
    s[t] += v;
    __syncthreads();
  }
  if (t < nb) btot[t] = s[t];
}

__global__ void scanC_rowptr_k(const int* __restrict__ a, const int* __restrict__ btot,
                               int* __restrict__ rowptr, int* __restrict__ cursor, int n){
  int g = blockIdx.x*blockDim.x + threadIdx.x;
  if (g >= n) return;
  int B = g >> 8;
  int off = (B > 0) ? btot[B-1] : 0;
  rowptr[g+1] = a[g] + off;
  cursor[g] = 0;
  if (g == 0) rowptr[0] = 0;
}

__global__ void scanC_above_k(const int* __restrict__ a, const int* __restrict__ btot,
                              int* __restrict__ habove, int nelems, int nbins){
  int g = blockIdx.x*blockDim.x + threadIdx.x;
  if (g >= nbins) return;
  int B = g >> 8;
  int off = (B > 0) ? btot[B-1] : 0;
  habove[g] = nelems - (a[g] + off);
}

// place src node index directly into csr slots of dst
__global__ void place_k(const int* __restrict__ dst, const int* __restrict__ msk,
                        const int* __restrict__ src, const int* __restrict__ rowptr,
                        int* __restrict__ cursor, int* __restrict__ csr, int e){
  int t = blockIdx.x*blockDim.x + threadIdx.x;
  if (t >= e) return;
  if (msk && !msk[t]) return;
  int d = dst[t];
  int slot = atomicAdd(&cursor[d], 1);
  csr[rowptr[d] + slot] = src[t];
}

// ---------------- per-node: segment max (in-register), softmax weights, pooling score ----
// g = i*4+h. Pass1: m = max(self, edges). Pass2: wse, wed (CSR-position-indexed, linear),
// score acc/den in CSR order (identical arithmetic order to prior rounds -> bit-exact).
__global__ void nodew_k(const double* __restrict__ als, const double* __restrict__ ald,
                        const double* __restrict__ hp, const int* __restrict__ csr,
                        const int* __restrict__ rowptr, const double* __restrict__ nrmbp,
                        double* __restrict__ wse, double* __restrict__ wed,
                        double* __restrict__ z, int n){
  int g = blockIdx.x*blockDim.x + threadIdx.x;
  int i = g>>2, h = g&3;
  if (i >= n) return;
  double aldv = ald[g];
  double selfev = lrelu(als[g] + aldv);
  int b = rowptr[i], e = rowptr[i+1];
  double m = selfev;
  for (int t=b; t<e; t++){
    int s = csr[t];
    double ev = lrelu(als[s*4+h] + aldv);
    m = fmax(m, ev);
  }
  double ws = exp(selfev - m);
  wse[g] = ws;
  double acc = ws * hp[g];
  double den = ws;
  for (int t=b; t<e; t++){
    int s = csr[t];
    double ev = lrelu(als[s*4+h] + aldv);
    double w = exp(ev - m);
    wed[(long)t*4+h] = w;
    acc = fma(w, hp[(long)s*4+h], acc);
    den += w;
  }
  double part = acc/den;
  part += __shfl_xor(part, 1);
  part += __shfl_xor(part, 2);
  if (h == 0) z[i] = (part + nrmbp[1]) / nrmbp[0];
}

// ---------------- per-head aggregation of raw features for kept nodes ----------------
template<typename TA>
__global__ void aggx4_k(const TA* __restrict__ X, const int* __restrict__ prm,
                        const int* __restrict__ rowptr, const int* __restrict__ csr,
                        const double* __restrict__ wed, const double* __restrict__ wse,
                        double* __restrict__ Xagg){
  int r = blockIdx.x, k = threadIdx.x;
  int i = prm[r];
  double w0 = wse[i*4+0], w1 = wse[i*4+1], w2 = wse[i*4+2], w3 = wse[i*4+3];
  double xv = (double)X[(long)i*256 + k];
  double a0=w0*xv, a1=w1*xv, a2=w2*xv, a3=w3*xv;
  double d0=w0, d1=w1, d2=w2, d3=w3;
  int b = rowptr[i], e = rowptr[i+1];
  for (int t=b; t<e; t++){
    int s = csr[t];
    double sv = (double)X[(long)s*256 + k];
    double e0=wed[(long)t*4+0], e1=wed[(long)t*4+1];
    double e2=wed[(long)t*4+2], e3=wed[(long)t*4+3];
    a0=fma(e0,sv,a0); a1=fma(e1,sv,a1); a2=fma(e2,sv,a2); a3=fma(e3,sv,a3);
    d0+=e0; d1+=e1; d2+=e2; d3+=e3;
  }
  long base = (long)r*1024 + k;
  Xagg[base      ] = a0/d0;
  Xagg[base + 256] = a1/d1;
  Xagg[base + 512] = a2/d2;
  Xagg[base + 768] = a3/d3;
}

// ---------------- GEMM + epilogue: Out[r][c] = relu(scs[r]*(Xagg_h@W_h + b)) ----------------
template<typename TO>
__global__ __launch_bounds__(256) void gemmE_k(const double* __restrict__ A,
                                               const float* __restrict__ W,
                                               const float* __restrict__ bias,
                                               const double* __restrict__ scs,
                                               TO* __restrict__ Out, int n){
  __shared__ double As[64][34];
  __shared__ double Bs[32][68];
  int tid = threadIdx.x;
  int r0 = blockIdx.x*64; int head = blockIdx.y; int c0 = head*64;
  int ty = tid>>4, tx = tid&15;
  double acc[4][4] = {};
  for (int k0=0; k0<256; k0+=32){
    int kA = tid&31, rA = tid>>5;
    #pragma unroll
    for (int i=0;i<8;i++){
      int rr = rA + i*8; int gr = r0+rr;
      As[rr][kA] = (gr<n) ? A[(long)gr*1024 + head*256 + k0 + kA] : 0.0;
    }
    int cB = tid&63, kB = tid>>6;
    #pragma unroll
    for (int i=0;i<8;i++){
      int kk = kB + i*4;
      Bs[kk][cB] = (double)W[(k0+kk)*256 + c0 + cB];
    }
    __syncthreads();
    #pragma unroll 4
    for (int k=0;k<32;k+=2){
      double2 a2[4];
      double blo[4], bhi[4];
      #pragma unroll
      for (int i=0;i<4;i++) a2[i] = *reinterpret_cast<const double2*>(&As[ty*4+i][k]);
      #pragma unroll
      for (int j=0;j<4;j++){ blo[j] = Bs[k][tx+16*j]; bhi[j] = Bs[k+1][tx+16*j]; }
      #pragma unroll
      for (int i=0;i<4;i++)
        #pragma unroll
        for (int j=0;j<4;j++) acc[i][j] = fma(a2[i].x, blo[j], acc[i][j]);
      #pragma unroll
      for (int i=0;i<4;i++)
        #pragma unroll
        for (int j=0;j<4;j++) acc[i][j] = fma(a2[i].y, bhi[j], acc[i][j]);
    }
    __syncthreads();
  }
  #pragma unroll
  for (int i=0;i<4;i++){
    int gr = r0 + ty*4 + i;
    if (gr < n){
      double s = scs[gr];
      #pragma unroll
      for (int j=0;j<4;j++){
        int c = c0 + tx + 16*j;
        double v = (acc[i][j] + (double)bias[c]) * s;
        Out[(long)gr*256 + c] = (TO)(v > 0.0 ? v : 0.0);
      }
    }
  }
}

// ||p|| and b.p
__global__ void pnorm_k(const float* __restrict__ p, const float* __restrict__ bias,
                        double* __restrict__ nrmbp){
  __shared__ double ws_[8];
  int tid = threadIdx.x;
  double pv = (double)p[tid];
  double v = pv*pv;
  double w = (double)bias[tid]*pv;
  for (int off=32; off; off>>=1){ v += __shfl_down(v, off); w += __shfl_down(w, off); }
  if ((tid&63)==0){ ws_[tid>>6] = v; ws_[4+(tid>>6)] = w; }
  __syncthreads();
  if (tid == 0){
    nrmbp[0] = sqrt(ws_[0]+ws_[1]+ws_[2]+ws_[3]);
    nrmbp[1] = ws_[4]+ws_[5]+ws_[6]+ws_[7];
  }
}

// ---------------- bucket-based exact ranking ----------------
__global__ void keyhist_k(const double* __restrict__ z, ull* __restrict__ k64,
                          int* __restrict__ hist, int n){
  int i = blockIdx.x*blockDim.x + threadIdx.x;
  if (i >= n) return;
  ull e = encd(z[i]);
  k64[i] = e;
  atomicAdd(&hist[(int)(e >> BSHIFT)], 1);
}

__global__ void bplace_k(const ull* __restrict__ k64, const int* __restrict__ habove,
                         int* __restrict__ cur, int* __restrict__ isort, int n){
  int i = blockIdx.x*blockDim.x + threadIdx.x;
  if (i >= n) return;
  int b = (int)(k64[i] >> BSHIFT);
  int slot = atomicAdd(&cur[b], 1);
  isort[habove[b] + slot] = i;
}

__global__ void brank_k(const ull* __restrict__ k64, const int* __restrict__ habove,
                        const int* __restrict__ isort, int* __restrict__ rank, int n){
  int i = blockIdx.x*blockDim.x + threadIdx.x;
  if (i >= n) return;
  ull ki = k64[i];
  int b = (int)(ki >> BSHIFT);
  int lo = habove[b];
  int hi = (b > 0) ? habove[b-1] : n;
  int cnt = 0;
  for (int t = lo; t < hi; t++){
    int j = isort[t];
    ull kj = k64[j];
    cnt += ((kj > ki) || (kj == ki && j < i)) ? 1 : 0;
  }
  rank[i] = lo + cnt;
}

__global__ void scatter_k(const double* __restrict__ z, const int* __restrict__ rank,
                          int* __restrict__ perm, int* __restrict__ inv,
                          double* __restrict__ scs, int n, int k){
  int i = blockIdx.x*blockDim.x + threadIdx.x;
  if (i >= n) return;
  int r = rank[i];
  inv[i] = (r < k) ? r : -1;
  if (r < k){ perm[r] = i; scs[r] = tanh(z[i]); }
}

__global__ void reindex_k(const int* __restrict__ src, const int* __restrict__ dst,
                          const int* __restrict__ inv,
                          int* __restrict__ ns, int* __restrict__ nd, int* __restrict__ nmsk, int e){
  int t = blockIdx.x*blockDim.x + threadIdx.x;
  if (t >= e) return;
  int a = inv[src[t]], b = inv[dst[t]];
  int ok = (a >= 0) && (b >= 0);
  ns[t] = ok ? a : 0; nd[t] = ok ? b : 0; nmsk[t] = ok;
}

__global__ void finedge_k(const int* __restrict__ ns, const int* __restrict__ nd,
                          const int* __restrict__ msk, const int* __restrict__ inv,
                          float* __restrict__ osrc, float* __restrict__ odst,
                          float* __restrict__ omsk, int e){
  int t = blockIdx.x*blockDim.x + threadIdx.x;
  if (t >= e) return;
  int a = inv[ns[t]], b = inv[nd[t]];
  int ok = msk[t] && (a >= 0) && (b >= 0);
  osrc[t] = (float)(ok ? a : 0);
  odst[t] = (float)(ok ? b : 0);
  omsk[t] = ok ? 1.0f : 0.0f;
}

__global__ void zerof_k(float* __restrict__ o, int n){
  int t = blockIdx.x*blockDim.x + threadIdx.x;
  if (t < n) o[t] = 0.0f;
}

extern "C" void kernel_launch(void* const* d_in, const int* in_sizes, int n_in,
                              void* d_out, int out_size, void* d_ws, size_t ws_size,
                              hipStream_t stream){
  (void)in_sizes; (void)n_in; (void)out_size; (void)ws_size;
  const float* x   = (const float*)d_in[0];
  const int*   ei  = (const int*)d_in[1];
  const float* W1  = (const float*)d_in[3];
  const float* as1 = (const float*)d_in[4];
  const float* ad1 = (const float*)d_in[5];
  const float* b1  = (const float*)d_in[6];
  const float* p1  = (const float*)d_in[7];
  const float* W2  = (const float*)d_in[8];
  const float* as2 = (const float*)d_in[9];
  const float* ad2 = (const float*)d_in[10];
  const float* b2  = (const float*)d_in[11];
  const float* p2  = (const float*)d_in[12];
  const int* src0 = ei;
  const int* dst0 = ei + EE;

  char* cur_ = (char*)d_ws;
  auto take = [&](size_t bytes)->void*{ void* p = (void*)cur_; cur_ += (bytes + 255) & ~(size_t)255; return p; };
  double* Xagg = (double*)take((size_t)12500*1024*8);   // 102.4 MB
  double* Xi   = (double*)take((size_t)KK1*256*8);
  double* als  = (double*)take((size_t)NN1*4*8);        // aliased by hist during ranking
  double* ald  = (double*)take((size_t)NN1*4*8);        // aliased by habove
  ull*    menc = (ull*)   take((size_t)NN1*4*8);        // aliased by bcur
  double* wse  = (double*)take((size_t)NN1*4*8);
  double* hp   = (double*)take((size_t)NN1*4*8);
  double* wed  = (double*)take((size_t)EE*4*8);
  double* sco  = (double*)take((size_t)NN1*8);
  double* scs  = (double*)take((size_t)KK1*8);
  double* nrm  = (double*)take(256);
  double* Q    = (double*)take((size_t)3072*8);
  ull*    k64  = (ull*)   take((size_t)NN1*8);
  int* isort= (int*)take((size_t)NN1*4);
  int* rnk  = (int*)take((size_t)NN1*4);
  int* prm  = (int*)take((size_t)KK1*4);
  int* inv  = (int*)take((size_t)NN1*4);
  int* deg  = (int*)take((size_t)(NN1+1)*4);
  int* rwp  = (int*)take((size_t)(NN1+1)*4);
  int* cursr= (int*)take((size_t)NN1*4);
  int* csr  = (int*)take((size_t)EE*4);
  int* ns   = (int*)take((size_t)EE*4);
  int* nd   = (int*)take((size_t)EE*4);
  int* mk2  = (int*)take((size_t)EE*4);
  int* btot = (int*)take((size_t)1024*4);

  int* hist   = (int*)als;
  int* habove = (int*)ald;
  int* bcur   = (int*)menc;

  float* out = (float*)d_out;
  float* o_x = out;
  float* o_s = out + (size_t)KK2*256;
  float* o_d = o_s + EE;
  float* o_m = o_d + EE;
  float* o_b = o_m + EE;

  // ---------------- stage 1 ----------------
  prepq_k<<<256,256,0,stream>>>(W1, as1, ad1, p1, Q);
  pnorm_k<<<1,256,0,stream>>>(p1, b1, nrm);
  matvec_k<float><<<CDIV(NN1,64),256,0,stream>>>(x, Q, als, ald, hp, NN1);
  zeroi_k<<<CDIV(NN1,256),256,0,stream>>>(deg, NN1);
  deg_k<<<CDIV(EE,256),256,0,stream>>>(dst0, nullptr, deg, EE);
  scanA_k<<<CDIV(NN1,256),256,0,stream>>>(deg, btot, NN1);
  scanB_k<<<1,1024,0,stream>>>(btot, CDIV(NN1,256));
  scanC_rowptr_k<<<CDIV(NN1,256),256,0,stream>>>(deg, btot, rwp, cursr, NN1);
  place_k<<<CDIV(EE,256),256,0,stream>>>(dst0, nullptr, src0, rwp, cursr, csr, EE);
  nodew_k<<<CDIV(NN1*4,256),256,0,stream>>>(als, ald, hp, csr, rwp, nrm, wse, wed, sco, NN1);

  // pool 1
  zero2_k<<<NB/256,256,0,stream>>>(hist, bcur, NB);
  keyhist_k<<<CDIV(NN1,256),256,0,stream>>>(sco, k64, hist, NN1);
  scanA_k<<<NB/256,256,0,stream>>>(hist, btot, NB);
  scanB_k<<<1,1024,0,stream>>>(btot, NB/256);
  scanC_above_k<<<NB/256,256,0,stream>>>(hist, btot, habove, NN1, NB);
  bplace_k<<<CDIV(NN1,256),256,0,stream>>>(k64, habove, bcur, isort, NN1);
  brank_k<<<CDIV(NN1,256),256,0,stream>>>(k64, habove, isort, rnk, NN1);
  scatter_k<<<CDIV(NN1,256),256,0,stream>>>(sco, rnk, prm, inv, scs, NN1, KK1);

  // gated features: two chunks of 12500 kept nodes
  aggx4_k<float><<<12500,256,0,stream>>>(x, prm, rwp, csr, wed, wse, Xagg);
  gemmE_k<double><<<dim3(CDIV(12500,64),4),256,0,stream>>>(Xagg, W1, b1, scs, Xi, 12500);
  aggx4_k<float><<<12500,256,0,stream>>>(x, prm+12500, rwp, csr, wed, wse, Xagg);
  gemmE_k<double><<<dim3(CDIV(12500,64),4),256,0,stream>>>(Xagg, W1, b1, scs+12500,
                                                           Xi+(size_t)12500*256, 12500);
  reindex_k<<<CDIV(EE,256),256,0,stream>>>(src0, dst0, inv, ns, nd, mk2, EE);

  // ---------------- stage 2 ----------------
  prepq_k<<<256,256,0,stream>>>(W2, as2, ad2, p2, Q);
  pnorm_k<<<1,256,0,stream>>>(p2, b2, nrm);
  matvec_k<double><<<CDIV(KK1,64),256,0,stream>>>(Xi, Q, als, ald, hp, KK1);
  zeroi_k<<<CDIV(KK1,256),256,0,stream>>>(deg, KK1);
  deg_k<<<CDIV(EE,256),256,0,stream>>>(nd, mk2, deg, EE);
  scanA_k<<<CDIV(KK1,256),256,0,stream>>>(deg, btot, KK1);
  scanB_k<<<1,1024,0,stream>>>(btot, CDIV(KK1,256));
  scanC_rowptr_k<<<CDIV(KK1,256),256,0,stream>>>(deg, btot, rwp, cursr, KK1);
  place_k<<<CDIV(EE,256),256,0,stream>>>(nd, mk2, ns, rwp, cursr, csr, EE);
  nodew_k<<<CDIV(KK1*4,256),256,0,stream>>>(als, ald, hp, csr, rwp, nrm, wse, wed, sco, KK1);

  // pool 2 + outputs
  zero2_k<<<NB/256,256,0,stream>>>(hist, bcur, NB);
  keyhist_k<<<CDIV(KK1,256),256,0,stream>>>(sco, k64, hist, KK1);
  scanA_k<<<NB/256,256,0,stream>>>(hist, btot, NB);
  scanB_k<<<1,1024,0,stream>>>(btot, NB/256);
  scanC_above_k<<<NB/256,256,0,stream>>>(hist, btot, habove, KK1, NB);
  bplace_k<<<CDIV(KK1,256),256,0,stream>>>(k64, habove, bcur, isort, KK1);
  brank_k<<<CDIV(KK1,256),256,0,stream>>>(k64, habove, isort, rnk, KK1);
  scatter_k<<<CDIV(KK1,256),256,0,stream>>>(sco, rnk, prm, inv, scs, KK1, KK2);

  aggx4_k<double><<<12500,256,0,stream>>>(Xi, prm, rwp, csr, wed, wse, Xagg);
  gemmE_k<float><<<dim3(CDIV(12500,64),4),256,0,stream>>>(Xagg, W2, b2, scs, o_x, 12500);
  finedge_k<<<CDIV(EE,256),256,0,stream>>>(ns, nd, mk2, inv, o_s, o_d, o_m, EE);
  zerof_k<<<CDIV(KK2,256),256,0,stream>>>(o_b, KK2);
}

// Round 10
// 779.192 us; speedup vs baseline: 1.5296x; 1.0178x over previous
//
#include <hip/hip_runtime.h>
#include <math.h>

typedef unsigned long long ull;

#define NN1 50000
#define EE  600000
#define KK1 25000
#define KK2 12500

#define NB (1<<18)      // rank buckets
#define BSHIFT 46       // 64-18

#define CDIV(a,b) (((a)+(b)-1)/(b))

__device__ __forceinline__ ull encd(double d){
  ull u = (ull)__double_as_longlong(d);
  return (u & 0x8000000000000000ULL) ? ~u : (u | 0x8000000000000000ULL);
}
__device__ __forceinline__ double lrelu(double z){ return z > 0.0 ? z : 0.2*z; }

__global__ void zeroi_k(int* __restrict__ p, int n){
  int t = blockIdx.x*blockDim.x + threadIdx.x;
  if (t < n) p[t] = 0;
}
__global__ void zero2_k(int* __restrict__ a, int* __restrict__ b, int n){
  int t = blockIdx.x*blockDim.x + threadIdx.x;
  if (t < n){ a[t] = 0; b[t] = 0; }
}

// ---------------- Q = [W.a_src | W.a_dst | W.p_heads] : [256][12] f64 ----------------
__global__ void prepq_k(const float* __restrict__ W, const float* __restrict__ as,
                        const float* __restrict__ ad, const float* __restrict__ p,
                        double* __restrict__ Q){
  int k = blockIdx.x; int ch = threadIdx.x; int head = ch>>6; int lane = ch&63;
  double w = (double)W[k*256 + ch];
  double vs = w*(double)as[ch], vd = w*(double)ad[ch], vp = w*(double)p[ch];
  for (int off=32; off; off>>=1){
    vs += __shfl_down(vs,off); vd += __shfl_down(vd,off); vp += __shfl_down(vp,off);
  }
  if (lane==0){ Q[k*12+head]=vs; Q[k*12+4+head]=vd; Q[k*12+8+head]=vp; }
}

// ---------------- matvec: als/ald/hp = A[n,256] @ Q[256,12], f64 ----------------
// Wave w owns k-quarter [64w,64w+64); lane = row. Direct global streaming (no staging
// barriers); wave-uniform Q index -> scalar loads. One barrier; fixed reduce order.
template<typename TA>
__global__ __launch_bounds__(256) void matvec_k(const TA* __restrict__ A, const double* __restrict__ Q,
                                                double* __restrict__ als, double* __restrict__ ald,
                                                double* __restrict__ hp, int n){
  __shared__ double P[4][64][13];
  int tid = threadIdx.x;
  int w = tid >> 6, l = tid & 63;
  int base = blockIdx.x*64;
  int r = base + l;
  double acc[12];
  #pragma unroll
  for (int j=0;j<12;j++) acc[j] = 0.0;
  if (r < n){
    const TA*    rowp = A + (size_t)r*256 + w*64;
    const double* qp  = Q + (size_t)w*64*12;
    if constexpr (sizeof(TA)==4){
      #pragma unroll 4
      for (int i=0;i<16;i++){
        float4 v = *reinterpret_cast<const float4*>(rowp + i*4);
        double e0=(double)v.x, e1=(double)v.y, e2=(double)v.z, e3=(double)v.w;
        #pragma unroll
        for (int j=0;j<12;j++) acc[j] = fma(e0, qp[(i*4+0)*12+j], acc[j]);
        #pragma unroll
        for (int j=0;j<12;j++) acc[j] = fma(e1, qp[(i*4+1)*12+j], acc[j]);
        #pragma unroll
        for (int j=0;j<12;j++) acc[j] = fma(e2, qp[(i*4+2)*12+j], acc[j]);
        #pragma unroll
        for (int j=0;j<12;j++) acc[j] = fma(e3, qp[(i*4+3)*12+j], acc[j]);
      }
    } else {
      #pragma unroll 4
      for (int i=0;i<32;i++){
        double2 v = *reinterpret_cast<const double2*>(rowp + i*2);
        #pragma unroll
        for (int j=0;j<12;j++) acc[j] = fma(v.x, qp[(i*2+0)*12+j], acc[j]);
        #pragma unroll
        for (int j=0;j<12;j++) acc[j] = fma(v.y, qp[(i*2+1)*12+j], acc[j]);
      }
    }
  }
  #pragma unroll
  for (int j=0;j<12;j++) P[w][l][j] = acc[j];
  __syncthreads();
  if (tid < 64){
    int rr = base + tid;
    if (rr < n){
      double s[12];
      #pragma unroll
      for (int j=0;j<12;j++)
        s[j] = ((P[0][tid][j] + P[1][tid][j]) + P[2][tid][j]) + P[3][tid][j];
      #pragma unroll
      for (int h=0;h<4;h++){
        als[rr*4+h] = s[h];
        ald[rr*4+h] = s[4+h];
        hp [rr*4+h] = s[8+h];
      }
    }
  }
}

__global__ void deg_k(const int* __restrict__ dst, const int* __restrict__ msk,
                      int* __restrict__ deg, int e){
  int t = blockIdx.x*blockDim.x + threadIdx.x;
  if (t >= e) return;
  if (msk && !msk[t]) return;
  atomicAdd(&deg[dst[t]], 1);
}

// ---------------- hierarchical scan (blocks of 256) ----------------
__global__ __launch_bounds__(256) void scanA_k(int* __restrict__ a, int* __restrict__ btot, int n){
  __shared__ int s[256];
  int g = blockIdx.x*256 + threadIdx.x;
  s[threadIdx.x] = (g < n) ? a[g] : 0;
  __syncthreads();
  for (int off=1; off<256; off<<=1){
    int t = (threadIdx.x >= off) ? s[threadIdx.x-off] : 0;
    __syncthreads();
    s[threadIdx.x] += t;
    __syncthreads();
  }
  if (g < n) a[g] = s[threadIdx.x];
  if (threadIdx.x == 255) btot[blockIdx.x] = s[255];
}

__global__ __launch_bounds__(1024) void scanB_k(int* __restrict__ btot, int nb){
  __shared__ int s[1024];
  int t = threadIdx.x;
  s[t] = (t < nb) ? btot[t] : 0;
  __syncthreads();
  for (int off=1; off<1024; off<<=1){
    int v = (t >= off) ? s[t-off] : 0;
    __syncthreads();
    s[t] += v;
    __syncthreads();
  }
  if (t < nb) btot[t] = s[t];
}

__global__ void scanC_rowptr_k(const int* __restrict__ a, const int* __restrict__ btot,
                               int* __restrict__ rowptr, int* __restrict__ cursor, int n){
  int g = blockIdx.x*blockDim.x + threadIdx.x;
  if (g >= n) return;
  int B = g >> 8;
  int off = (B > 0) ? btot[B-1] : 0;
  rowptr[g+1] = a[g] + off;
  cursor[g] = 0;
  if (g == 0) rowptr[0] = 0;
}

__global__ void scanC_above_k(const int* __restrict__ a, const int* __restrict__ btot,
                              int* __restrict__ habove, int nelems, int nbins){
  int g = blockIdx.x*blockDim.x + threadIdx.x;
  if (g >= nbins) return;
  int B = g >> 8;
  int off = (B > 0) ? btot[B-1] : 0;
  habove[g] = nelems - (a[g] + off);
}

// place src node index directly into csr slots of dst
__global__ void place_k(const int* __restrict__ dst, const int* __restrict__ msk,
                        const int* __restrict__ src, const int* __restrict__ rowptr,
                        int* __restrict__ cursor, int* __restrict__ csr, int e){
  int t = blockIdx.x*blockDim.x + threadIdx.x;
  if (t >= e) return;
  if (msk && !msk[t]) return;
  int d = dst[t];
  int slot = atomicAdd(&cursor[d], 1);
  csr[rowptr[d] + slot] = src[t];
}

// ---------------- per-node: segment max, softmax weights, pooling score ----------------
__global__ void nodew_k(const double* __restrict__ als, const double* __restrict__ ald,
                        const double* __restrict__ hp, const int* __restrict__ csr,
                        const int* __restrict__ rowptr, const double* __restrict__ nrmbp,
                        double* __restrict__ wse, double* __restrict__ wed,
                        double* __restrict__ z, int n){
  int g = blockIdx.x*blockDim.x + threadIdx.x;
  int i = g>>2, h = g&3;
  if (i >= n) return;
  double aldv = ald[g];
  double selfev = lrelu(als[g] + aldv);
  int b = rowptr[i], e = rowptr[i+1];
  double m = selfev;
  for (int t=b; t<e; t++){
    int s = csr[t];
    double ev = lrelu(als[s*4+h] + aldv);
    m = fmax(m, ev);
  }
  double ws = exp(selfev - m);
  wse[g] = ws;
  double acc = ws * hp[g];
  double den = ws;
  for (int t=b; t<e; t++){
    int s = csr[t];
    double ev = lrelu(als[s*4+h] + aldv);
    double w = exp(ev - m);
    wed[(long)t*4+h] = w;
    acc = fma(w, hp[(long)s*4+h], acc);
    den += w;
  }
  double part = acc/den;
  part += __shfl_xor(part, 1);
  part += __shfl_xor(part, 2);
  if (h == 0) z[i] = (part + nrmbp[1]) / nrmbp[0];
}

// ---------------- per-head aggregation of raw features for kept nodes ----------------
template<typename TA>
__global__ void aggx4_k(const TA* __restrict__ X, const int* __restrict__ prm,
                        const int* __restrict__ rowptr, const int* __restrict__ csr,
                        const double* __restrict__ wed, const double* __restrict__ wse,
                        double* __restrict__ Xagg){
  int r = blockIdx.x, k = threadIdx.x;
  int i = prm[r];
  double w0 = wse[i*4+0], w1 = wse[i*4+1], w2 = wse[i*4+2], w3 = wse[i*4+3];
  double xv = (double)X[(long)i*256 + k];
  double a0=w0*xv, a1=w1*xv, a2=w2*xv, a3=w3*xv;
  double d0=w0, d1=w1, d2=w2, d3=w3;
  int b = rowptr[i], e = rowptr[i+1];
  for (int t=b; t<e; t++){
    int s = csr[t];
    double sv = (double)X[(long)s*256 + k];
    double e0=wed[(long)t*4+0], e1=wed[(long)t*4+1];
    double e2=wed[(long)t*4+2], e3=wed[(long)t*4+3];
    a0=fma(e0,sv,a0); a1=fma(e1,sv,a1); a2=fma(e2,sv,a2); a3=fma(e3,sv,a3);
    d0+=e0; d1+=e1; d2+=e2; d3+=e3;
  }
  long base = (long)r*1024 + k;
  Xagg[base      ] = a0/d0;
  Xagg[base + 256] = a1/d1;
  Xagg[base + 512] = a2/d2;
  Xagg[base + 768] = a3/d3;
}

// ---------------- GEMM + epilogue: Out[r][c] = relu(scs[r]*(Xagg_h@W_h + b)) ----------------
template<typename TO>
__global__ __launch_bounds__(256) void gemmE_k(const double* __restrict__ A,
                                               const float* __restrict__ W,
                                               const float* __restrict__ bias,
                                               const double* __restrict__ scs,
                                               TO* __restrict__ Out, int n){
  __shared__ double As[64][34];
  __shared__ double Bs[32][68];
  int tid = threadIdx.x;
  int r0 = blockIdx.x*64; int head = blockIdx.y; int c0 = head*64;
  int ty = tid>>4, tx = tid&15;
  double acc[4][4] = {};
  for (int k0=0; k0<256; k0+=32){
    int kA = tid&31, rA = tid>>5;
    #pragma unroll
    for (int i=0;i<8;i++){
      int rr = rA + i*8; int gr = r0+rr;
      As[rr][kA] = (gr<n) ? A[(long)gr*1024 + head*256 + k0 + kA] : 0.0;
    }
    int cB = tid&63, kB = tid>>6;
    #pragma unroll
    for (int i=0;i<8;i++){
      int kk = kB + i*4;
      Bs[kk][cB] = (double)W[(k0+kk)*256 + c0 + cB];
    }
    __syncthreads();
    #pragma unroll 4
    for (int k=0;k<32;k+=2){
      double2 a2[4];
      double blo[4], bhi[4];
      #pragma unroll
      for (int i=0;i<4;i++) a2[i] = *reinterpret_cast<const double2*>(&As[ty*4+i][k]);
      #pragma unroll
      for (int j=0;j<4;j++){ blo[j] = Bs[k][tx+16*j]; bhi[j] = Bs[k+1][tx+16*j]; }
      #pragma unroll
      for (int i=0;i<4;i++)
        #pragma unroll
        for (int j=0;j<4;j++) acc[i][j] = fma(a2[i].x, blo[j], acc[i][j]);
      #pragma unroll
      for (int i=0;i<4;i++)
        #pragma unroll
        for (int j=0;j<4;j++) acc[i][j] = fma(a2[i].y, bhi[j], acc[i][j]);
    }
    __syncthreads();
  }
  #pragma unroll
  for (int i=0;i<4;i++){
    int gr = r0 + ty*4 + i;
    if (gr < n){
      double s = scs[gr];
      #pragma unroll
      for (int j=0;j<4;j++){
        int c = c0 + tx + 16*j;
        double v = (acc[i][j] + (double)bias[c]) * s;
        Out[(long)gr*256 + c] = (TO)(v > 0.0 ? v : 0.0);
      }
    }
  }
}

// ||p|| and b.p
__global__ void pnorm_k(const float* __restrict__ p, const float* __restrict__ bias,
                        double* __restrict__ nrmbp){
  __shared__ double ws_[8];
  int tid = threadIdx.x;
  double pv = (double)p[tid];
  double v = pv*pv;
  double w = (double)bias[tid]*pv;
  for (int off=32; off; off>>=1){ v += __shfl_down(v, off); w += __shfl_down(w, off); }
  if ((tid&63)==0){ ws_[tid>>6] = v; ws_[4+(tid>>6)] = w; }
  __syncthreads();
  if (tid == 0){
    nrmbp[0] = sqrt(ws_[0]+ws_[1]+ws_[2]+ws_[3]);
    nrmbp[1] = ws_[4]+ws_[5]+ws_[6]+ws_[7];
  }
}

// ---------------- bucket-based exact ranking ----------------
__global__ void keyhist_k(const double* __restrict__ z, ull* __restrict__ k64,
                          int* __restrict__ hist, int n){
  int i = blockIdx.x*blockDim.x + threadIdx.x;
  if (i >= n) return;
  ull e = encd(z[i]);
  k64[i] = e;
  atomicAdd(&hist[(int)(e >> BSHIFT)], 1);
}

__global__ void bplace_k(const ull* __restrict__ k64, const int* __restrict__ habove,
                         int* __restrict__ cur, int* __restrict__ isort, int n){
  int i = blockIdx.x*blockDim.x + threadIdx.x;
  if (i >= n) return;
  int b = (int)(k64[i] >> BSHIFT);
  int slot = atomicAdd(&cur[b], 1);
  isort[habove[b] + slot] = i;
}

__global__ void brank_k(const ull* __restrict__ k64, const int* __restrict__ habove,
                        const int* __restrict__ isort, int* __restrict__ rank, int n){
  int i = blockIdx.x*blockDim.x + threadIdx.x;
  if (i >= n) return;
  ull ki = k64[i];
  int b = (int)(ki >> BSHIFT);
  int lo = habove[b];
  int hi = (b > 0) ? habove[b-1] : n;
  int cnt = 0;
  for (int t = lo; t < hi; t++){
    int j = isort[t];
    ull kj = k64[j];
    cnt += ((kj > ki) || (kj == ki && j < i)) ? 1 : 0;
  }
  rank[i] = lo + cnt;
}

__global__ void scatter_k(const double* __restrict__ z, const int* __restrict__ rank,
                          int* __restrict__ perm, int* __restrict__ inv,
                          double* __restrict__ scs, int n, int k){
  int i = blockIdx.x*blockDim.x + threadIdx.x;
  if (i >= n) return;
  int r = rank[i];
  inv[i] = (r < k) ? r : -1;
  if (r < k){ perm[r] = i; scs[r] = tanh(z[i]); }
}

__global__ void reindex_k(const int* __restrict__ src, const int* __restrict__ dst,
                          const int* __restrict__ inv,
                          int* __restrict__ ns, int* __restrict__ nd, int* __restrict__ nmsk, int e){
  int t = blockIdx.x*blockDim.x + threadIdx.x;
  if (t >= e) return;
  int a = inv[src[t]], b = inv[dst[t]];
  int ok = (a >= 0) && (b >= 0);
  ns[t] = ok ? a : 0; nd[t] = ok ? b : 0; nmsk[t] = ok;
}

__global__ void finedge_k(const int* __restrict__ ns, const int* __restrict__ nd,
                          const int* __restrict__ msk, const int* __restrict__ inv,
                          float* __restrict__ osrc, float* __restrict__ odst,
                          float* __restrict__ omsk, int e){
  int t = blockIdx.x*blockDim.x + threadIdx.x;
  if (t >= e) return;
  int a = inv[ns[t]], b = inv[nd[t]];
  int ok = msk[t] && (a >= 0) && (b >= 0);
  osrc[t] = (float)(ok ? a : 0);
  odst[t] = (float)(ok ? b : 0);
  omsk[t] = ok ? 1.0f : 0.0f;
}

__global__ void zerof_k(float* __restrict__ o, int n){
  int t = blockIdx.x*blockDim.x + threadIdx.x;
  if (t < n) o[t] = 0.0f;
}

extern "C" void kernel_launch(void* const* d_in, const int* in_sizes, int n_in,
                              void* d_out, int out_size, void* d_ws, size_t ws_size,
                              hipStream_t stream){
  (void)in_sizes; (void)n_in; (void)out_size; (void)ws_size;
  const float* x   = (const float*)d_in[0];
  const int*   ei  = (const int*)d_in[1];
  const float* W1  = (const float*)d_in[3];
  const float* as1 = (const float*)d_in[4];
  const float* ad1 = (const float*)d_in[5];
  const float* b1  = (const float*)d_in[6];
  const float* p1  = (const float*)d_in[7];
  const float* W2  = (const float*)d_in[8];
  const float* as2 = (const float*)d_in[9];
  const float* ad2 = (const float*)d_in[10];
  const float* b2  = (const float*)d_in[11];
  const float* p2  = (const float*)d_in[12];
  const int* src0 = ei;
  const int* dst0 = ei + EE;

  char* cur_ = (char*)d_ws;
  auto take = [&](size_t bytes)->void*{ void* p = (void*)cur_; cur_ += (bytes + 255) & ~(size_t)255; return p; };
  double* Xagg = (double*)take((size_t)12500*1024*8);   // 102.4 MB
  double* Xi   = (double*)take((size_t)KK1*256*8);
  double* als  = (double*)take((size_t)NN1*4*8);        // aliased by hist during ranking
  double* ald  = (double*)take((size_t)NN1*4*8);        // aliased by habove
  ull*    menc = (ull*)   take((size_t)NN1*4*8);        // aliased by bcur
  double* wse  = (double*)take((size_t)NN1*4*8);
  double* hp   = (double*)take((size_t)NN1*4*8);
  double* wed  = (double*)take((size_t)EE*4*8);
  double* sco  = (double*)take((size_t)NN1*8);
  double* scs  = (double*)take((size_t)KK1*8);
  double* nrm  = (double*)take(256);
  double* Q    = (double*)take((size_t)3072*8);
  ull*    k64  = (ull*)   take((size_t)NN1*8);
  int* isort= (int*)take((size_t)NN1*4);
  int* rnk  = (int*)take((size_t)NN1*4);
  int* prm  = (int*)take((size_t)KK1*4);
  int* inv  = (int*)take((size_t)NN1*4);
  int* deg  = (int*)take((size_t)(NN1+1)*4);
  int* rwp  = (int*)take((size_t)(NN1+1)*4);
  int* cursr= (int*)take((size_t)NN1*4);
  int* csr  = (int*)take((size_t)EE*4);
  int* ns   = (int*)take((size_t)EE*4);
  int* nd   = (int*)take((size_t)EE*4);
  int* mk2  = (int*)take((size_t)EE*4);
  int* btot = (int*)take((size_t)1024*4);

  int* hist   = (int*)als;
  int* habove = (int*)ald;
  int* bcur   = (int*)menc;

  float* out = (float*)d_out;
  float* o_x = out;
  float* o_s = out + (size_t)KK2*256;
  float* o_d = o_s + EE;
  float* o_m = o_d + EE;
  float* o_b = o_m + EE;

  // ---------------- stage 1 ----------------
  prepq_k<<<256,256,0,stream>>>(W1, as1, ad1, p1, Q);
  pnorm_k<<<1,256,0,stream>>>(p1, b1, nrm);
  matvec_k<float><<<CDIV(NN1,64),256,0,stream>>>(x, Q, als, ald, hp, NN1);
  zeroi_k<<<CDIV(NN1,256),256,0,stream>>>(deg, NN1);
  deg_k<<<CDIV(EE,256),256,0,stream>>>(dst0, nullptr, deg, EE);
  scanA_k<<<CDIV(NN1,256),256,0,stream>>>(deg, btot, NN1);
  scanB_k<<<1,1024,0,stream>>>(btot, CDIV(NN1,256));
  scanC_rowptr_k<<<CDIV(NN1,256),256,0,stream>>>(deg, btot, rwp, cursr, NN1);
  place_k<<<CDIV(EE,256),256,0,stream>>>(dst0, nullptr, src0, rwp, cursr, csr, EE);
  nodew_k<<<CDIV(NN1*4,256),256,0,stream>>>(als, ald, hp, csr, rwp, nrm, wse, wed, sco, NN1);

  // pool 1
  zero2_k<<<NB/256,256,0,stream>>>(hist, bcur, NB);
  keyhist_k<<<CDIV(NN1,256),256,0,stream>>>(sco, k64, hist, NN1);
  scanA_k<<<NB/256,256,0,stream>>>(hist, btot, NB);
  scanB_k<<<1,1024,0,stream>>>(btot, NB/256);
  scanC_above_k<<<NB/256,256,0,stream>>>(hist, btot, habove, NN1, NB);
  bplace_k<<<CDIV(NN1,256),256,0,stream>>>(k64, habove, bcur, isort, NN1);
  brank_k<<<CDIV(NN1,256),256,0,stream>>>(k64, habove, isort, rnk, NN1);
  scatter_k<<<CDIV(NN1,256),256,0,stream>>>(sco, rnk, prm, inv, scs, NN1, KK1);

  // gated features: two chunks of 12500 kept nodes
  aggx4_k<float><<<12500,256,0,stream>>>(x, prm, rwp, csr, wed, wse, Xagg);
  gemmE_k<double><<<dim3(CDIV(12500,64),4),256,0,stream>>>(Xagg, W1, b1, scs, Xi, 12500);
  aggx4_k<float><<<12500,256,0,stream>>>(x, prm+12500, rwp, csr, wed, wse, Xagg);
  gemmE_k<double><<<dim3(CDIV(12500,64),4),256,0,stream>>>(Xagg, W1, b1, scs+12500,
                                                           Xi+(size_t)12500*256, 12500);
  reindex_k<<<CDIV(EE,256),256,0,stream>>>(src0, dst0, inv, ns, nd, mk2, EE);

  // ---------------- stage 2 ----------------
  prepq_k<<<256,256,0,stream>>>(W2, as2, ad2, p2, Q);
  pnorm_k<<<1,256,0,stream>>>(p2, b2, nrm);
  matvec_k<double><<<CDIV(KK1,64),256,0,stream>>>(Xi, Q, als, ald, hp, KK1);
  zeroi_k<<<CDIV(KK1,256),256,0,stream>>>(deg, KK1);
  deg_k<<<CDIV(EE,256),256,0,stream>>>(nd, mk2, deg, EE);
  scanA_k<<<CDIV(KK1,256),256,0,stream>>>(deg, btot, KK1);
  scanB_k<<<1,1024,0,stream>>>(btot, CDIV(KK1,256));
  scanC_rowptr_k<<<CDIV(KK1,256),256,0,stream>>>(deg, btot, rwp, cursr, KK1);
  place_k<<<CDIV(EE,256),256,0,stream>>>(nd, mk2, ns, rwp, cursr, csr, EE);
  nodew_k<<<CDIV(KK1*4,256),256,0,stream>>>(als, ald, hp, csr, rwp, nrm, wse, wed, sco, KK1);

  // pool 2 + outputs
  zero2_k<<<NB/256,256,0,stream>>>(hist, bcur, NB);
  keyhist_k<<<CDIV(KK1,256),256,0,stream>>>(sco, k64, hist, KK1);
  scanA_k<<<NB/256,256,0,stream>>>(hist, btot, NB);
  scanB_k<<<1,1024,0,stream>>>(btot, NB/256);
  scanC_above_k<<<NB/256,256,0,stream>>>(hist, btot, habove, KK1, NB);
  bplace_k<<<CDIV(KK1,256),256,0,stream>>>(k64, habove, bcur, isort, KK1);
  brank_k<<<CDIV(KK1,256),256,0,stream>>>(k64, habove, isort, rnk, KK1);
  scatter_k<<<CDIV(KK1,256),256,0,stream>>>(sco, rnk, prm, inv, scs, KK1, KK2);

  aggx4_k<double><<<12500,256,0,stream>>>(Xi, prm, rwp, csr, wed, wse, Xagg);
  gemmE_k<float><<<dim3(CDIV(12500,64),4),256,0,stream>>>(Xagg, W2, b2, scs, o_x, 12500);
  finedge_k<<<CDIV(EE,256),256,0,stream>>>(ns, nd, mk2, inv, o_s, o_d, o_m, EE);
  zerof_k<<<CDIV(KK2,256),256,0,stream>>>(o_b, KK2);
}